// Round 5
// baseline (4222.917 us; speedup 1.0000x reference)
//
#include <hip/hip_runtime.h>
#include <hip/hip_bf16.h>
#include <math.h>

constexpr int NP  = 32768;  // mesh points
constexpr int HH  = 8;      // heads

typedef short bf16x8 __attribute__((ext_vector_type(8)));
typedef float f32x4  __attribute__((ext_vector_type(4)));

__device__ __forceinline__ float gelu_f(float x) {
    return 0.5f * x * (1.0f + erff(x * 0.70710678118654752f));
}

__device__ __forceinline__ unsigned short f2bf(float x) {
    union { float f; unsigned u; } v; v.f = x;
    unsigned r = v.u + 0x7fffu + ((v.u >> 16) & 1u);
    return (unsigned short)(r >> 16);
}

// ---------------------------------------------------------------------------
// Weight prep: src [G][K][256] fp32 -> dst [G][256][K] bf16 (transposed)
// ---------------------------------------------------------------------------
__global__ __launch_bounds__(256) void transpose_bf16_k(
    const float* __restrict__ src, unsigned short* __restrict__ dst, int K)
{
    __shared__ float tile[32][33];
    int g = blockIdx.z;
    int k0 = blockIdx.x * 32, c0 = blockIdx.y * 32;
    int tx = threadIdx.x & 31, ty = threadIdx.x >> 5;
    const float* s = src + (size_t)g * K * 256;
    unsigned short* d = dst + (size_t)g * 256 * K;
    #pragma unroll
    for (int rr = 0; rr < 4; ++rr) {
        int r = ty + rr * 8;
        tile[r][tx] = s[(size_t)(k0 + r) * 256 + c0 + tx];
    }
    __syncthreads();
    #pragma unroll
    for (int rr = 0; rr < 4; ++rr) {
        int r = ty + rr * 8;
        d[(size_t)(c0 + r) * K + k0 + tx] = f2bf(tile[tx][r]);
    }
}

// ---------------------------------------------------------------------------
// MFMA GEMM (unchanged): C = epi( A'[N x K] @ W[K x 256] + bias )
// ---------------------------------------------------------------------------
template<bool GENA, bool LNIN, bool DOGELU, bool RESID, bool STATS, bool PERM>
__global__ __launch_bounds__(256) void gemm_mfma(
    const float* __restrict__ A, const unsigned short* __restrict__ Wt,
    const float* __restrict__ bias, const float* __restrict__ bias2,
    float* __restrict__ Cout,
    const float* __restrict__ stats_in, float* __restrict__ stats_out,
    const float* __restrict__ lng, const float* __restrict__ lnb,
    const float* __restrict__ genx, const float* __restrict__ genw1,
    const float* __restrict__ genb1, int K)
{
    __shared__ __align__(16) unsigned short As[128 * 64];
    __shared__ __align__(16) unsigned short Bs[128 * 64];
    __shared__ float rmean[LNIN ? 128 : 1];
    __shared__ float rrstd[LNIN ? 128 : 1];
    __shared__ float w1s[GENA ? 1536 : 1];
    __shared__ float b1s[GENA ? 512 : 1];
    __shared__ float x3s[GENA ? 512 : 1];

    const int tid = threadIdx.x;
    const int rBase = blockIdx.x * 128, cBase = blockIdx.y * 128;

    if constexpr (GENA) {
        for (int i2 = tid; i2 < 1536; i2 += 256) w1s[i2] = genw1[i2];
        for (int i2 = tid; i2 < 512; i2 += 256) b1s[i2] = genb1[i2];
        if (tid < 128) {
            x3s[tid * 4 + 0] = genx[(size_t)(rBase + tid) * 3 + 0];
            x3s[tid * 4 + 1] = genx[(size_t)(rBase + tid) * 3 + 1];
            x3s[tid * 4 + 2] = genx[(size_t)(rBase + tid) * 3 + 2];
        }
        __syncthreads();
    }
    if constexpr (LNIN) {
        if (tid < 128) {
            const float* sp = stats_in + (size_t)(rBase + tid) * 8;
            float4 s0 = *(const float4*)sp;
            float4 s1 = *(const float4*)(sp + 4);
            float mean = (s0.x + s0.z + s1.x + s1.z) * (1.f / 256.f);
            float ex2  = (s0.y + s0.w + s1.y + s1.w) * (1.f / 256.f);
            rmean[tid] = mean;
            rrstd[tid] = rsqrtf(fmaxf(ex2 - mean * mean, 0.f) + 1e-5f);
        }
        __syncthreads();
    }

    f32x4 acc[4][4];
    #pragma unroll
    for (int i = 0; i < 4; ++i)
        #pragma unroll
        for (int j = 0; j < 4; ++j)
            acc[i][j] = (f32x4){0.f, 0.f, 0.f, 0.f};

    const int lane = tid & 63, wid = tid >> 6;
    const int wr = wid >> 1, wc = wid & 1;
    const int lrow = lane & 15, quad = lane >> 4;
    const int srow = tid >> 3;   // 0..31
    const int sch  = tid & 7;    // k-chunk of 8

    for (int kc = 0; kc < K; kc += 64) {
        #pragma unroll
        for (int it = 0; it < 4; ++it) {
            int row = srow + it * 32;
            float v[8];
            if constexpr (GENA) {
                float x0 = x3s[row * 4 + 0], x1 = x3s[row * 4 + 1], x2 = x3s[row * 4 + 2];
                #pragma unroll
                for (int j = 0; j < 8; ++j) {
                    int k = kc + sch * 8 + j;
                    float t = x0 * w1s[k] + x1 * w1s[512 + k] + x2 * w1s[1024 + k] + b1s[k];
                    v[j] = gelu_f(t);
                }
            } else {
                const float* ap = A + (size_t)(rBase + row) * 256 + kc + sch * 8;
                float4 a0 = *(const float4*)ap;
                float4 a1 = *(const float4*)(ap + 4);
                v[0] = a0.x; v[1] = a0.y; v[2] = a0.z; v[3] = a0.w;
                v[4] = a1.x; v[5] = a1.y; v[6] = a1.z; v[7] = a1.w;
                if constexpr (LNIN) {
                    float m = rmean[row], rs = rrstd[row];
                    const float* gp = lng + kc + sch * 8;
                    const float* bp = lnb + kc + sch * 8;
                    float4 g0 = *(const float4*)gp, g1 = *(const float4*)(gp + 4);
                    float4 c0 = *(const float4*)bp, c1 = *(const float4*)(bp + 4);
                    float gg[8] = {g0.x, g0.y, g0.z, g0.w, g1.x, g1.y, g1.z, g1.w};
                    float bb[8] = {c0.x, c0.y, c0.z, c0.w, c1.x, c1.y, c1.z, c1.w};
                    #pragma unroll
                    for (int j = 0; j < 8; ++j) v[j] = (v[j] - m) * rs * gg[j] + bb[j];
                }
            }
            unsigned short pk[8];
            #pragma unroll
            for (int j = 0; j < 8; ++j) pk[j] = f2bf(v[j]);
            *(uint4*)&As[row * 64 + ((sch ^ (row & 7)) << 3)] = *(uint4*)pk;
        }
        #pragma unroll
        for (int it = 0; it < 4; ++it) {
            int n = srow + it * 32;
            uint4 wv_ = *(const uint4*)(Wt + (size_t)(cBase + n) * K + kc + sch * 8);
            *(uint4*)&Bs[n * 64 + ((sch ^ (n & 7)) << 3)] = wv_;
        }
        __syncthreads();
        #pragma unroll
        for (int ks = 0; ks < 2; ++ks) {
            bf16x8 af[4], bfr[4];
            #pragma unroll
            for (int t = 0; t < 4; ++t) {
                int row = wr * 64 + t * 16 + lrow;
                af[t] = *(bf16x8*)&As[row * 64 + (((ks * 4 + quad) ^ (row & 7)) << 3)];
                int n = wc * 64 + t * 16 + lrow;
                bfr[t] = *(bf16x8*)&Bs[n * 64 + (((ks * 4 + quad) ^ (n & 7)) << 3)];
            }
            #pragma unroll
            for (int ti = 0; ti < 4; ++ti)
                #pragma unroll
                for (int tj = 0; tj < 4; ++tj)
                    acc[ti][tj] = __builtin_amdgcn_mfma_f32_16x16x32_bf16(
                        af[ti], bfr[tj], acc[ti][tj], 0, 0, 0);
        }
        __syncthreads();
    }

    float bcol[4];
    #pragma unroll
    for (int tj = 0; tj < 4; ++tj) {
        int gcol = cBase + wc * 64 + tj * 16 + lrow;
        float b = bias[gcol];
        if (bias2) b += bias2[gcol];
        bcol[tj] = b;
    }
    #pragma unroll
    for (int ti = 0; ti < 4; ++ti) {
        #pragma unroll
        for (int r = 0; r < 4; ++r) {
            int grow = rBase + wr * 64 + ti * 16 + quad * 4 + r;
            float vv[4];
            #pragma unroll
            for (int tj = 0; tj < 4; ++tj) {
                float v = acc[ti][tj][r] + bcol[tj];
                if constexpr (DOGELU) v = gelu_f(v);
                vv[tj] = v;
            }
            if constexpr (RESID) {
                #pragma unroll
                for (int tj = 0; tj < 4; ++tj) {
                    int gcol = cBase + wc * 64 + tj * 16 + lrow;
                    vv[tj] += Cout[(size_t)grow * 256 + gcol];
                }
            }
            if constexpr (STATS) {
                float rs = vv[0] + vv[1] + vv[2] + vv[3];
                float rq = vv[0]*vv[0] + vv[1]*vv[1] + vv[2]*vv[2] + vv[3]*vv[3];
                #pragma unroll
                for (int m = 1; m < 16; m <<= 1) {
                    rs += __shfl_xor(rs, m);
                    rq += __shfl_xor(rq, m);
                }
                if (lrow == 0) {
                    stats_out[(size_t)grow * 8 + (blockIdx.y * 2 + wc) * 2 + 0] = rs;
                    stats_out[(size_t)grow * 8 + (blockIdx.y * 2 + wc) * 2 + 1] = rq;
                }
            }
            #pragma unroll
            for (int tj = 0; tj < 4; ++tj) {
                int gcol = cBase + wc * 64 + tj * 16 + lrow;
                if constexpr (PERM)
                    Cout[(size_t)(gcol >> 5) * NP * 32 + (size_t)grow * 32 + (gcol & 31)] = vv[tj];
                else
                    Cout[(size_t)grow * 256 + gcol] = vv[tj];
            }
        }
    }
}

// ---------------------------------------------------------------------------
// kv3: 512 threads; thread (p=tid>>6, dg=tid&63) owns d={2dg,2dg+1} x 32 c.
// R5 fix: epilogue fully unrolled -> all acc indices compile-time -> arrays
// stay in VGPRs (R4 had runtime cc -> whole acc array in scratch -> 500 MB
// HBM leak and 310 us).
// partials layout: [h][chunk][4224] = 128*32 kv + 128 sumexp
// ---------------------------------------------------------------------------
__global__ __launch_bounds__(512, 4) void kv3_kernel(
    const float* __restrict__ xm2, const float* __restrict__ wk,
    const float* __restrict__ wv, const float* __restrict__ tk_arr,
    float* __restrict__ partials, int layer)
{
    __shared__ __align__(16) float smem[9216];
    float* xs  = smem;            // [64][32]
    float* vs  = smem + 2048;     // [64][32]
    float* wks = smem + 4096;     // wk linear [32][128]
    float* wvs = smem + 8192;     // [32][32]
    float* red = smem;            // [512][9] alias

    const int tid = threadIdx.x;
    const int h = blockIdx.y;
    const int rowBase = blockIdx.x * 512;
    const int p  = tid >> 6;
    const int dg = tid & 63;

    float tk = fminf(fmaxf(tk_arr[layer * 8 + h], 0.1f), 2.0f);
    float invtk = 1.0f / tk;
    for (int i = tid; i < 4096; i += 512) wks[i] = wk[i];
    for (int i = tid; i < 1024; i += 512) wvs[i] = wv[i];

    float acc0[32], acc1[32];
    #pragma unroll
    for (int c = 0; c < 32; ++c) { acc0[c] = 0.f; acc1[c] = 0.f; }
    float se0 = 0.f, se1 = 0.f;

    const float* src = xm2 + (size_t)h * NP * 32 + (size_t)rowBase * 32;
    const int lr = tid >> 3, lc = (tid & 7) * 4;

    for (int tile = 0; tile < 8; ++tile) {
        __syncthreads();
        *(float4*)&xs[lr * 32 + lc] =
            *(const float4*)(src + (size_t)(tile * 64 + lr) * 32 + lc);
        __syncthreads();
        {
            float a0 = 0.f, a1 = 0.f, a2 = 0.f, a3 = 0.f;
            #pragma unroll
            for (int j = 0; j < 32; ++j) {
                float xv = xs[lr * 32 + j];
                float4 w4 = *(const float4*)&wvs[j * 32 + lc];
                a0 += xv * w4.x; a1 += xv * w4.y; a2 += xv * w4.z; a3 += xv * w4.w;
            }
            float4 o; o.x = a0; o.y = a1; o.z = a2; o.w = a3;
            *(float4*)&vs[lr * 32 + lc] = o;
        }
        __syncthreads();
        #pragma unroll 1
        for (int t = 0; t < 8; ++t) {
            int n = p * 8 + t;
            float l0 = 0.f, l1 = 0.f;
            #pragma unroll
            for (int j4 = 0; j4 < 8; ++j4) {
                float4 x4 = *(const float4*)&xs[n * 32 + j4 * 4];
                float2 wA = *(const float2*)&wks[((j4 * 4 + 0) * 64 + dg) * 2];
                float2 wB = *(const float2*)&wks[((j4 * 4 + 1) * 64 + dg) * 2];
                float2 wC = *(const float2*)&wks[((j4 * 4 + 2) * 64 + dg) * 2];
                float2 wD = *(const float2*)&wks[((j4 * 4 + 3) * 64 + dg) * 2];
                l0 += x4.x * wA.x + x4.y * wB.x + x4.z * wC.x + x4.w * wD.x;
                l1 += x4.x * wA.y + x4.y * wB.y + x4.z * wC.y + x4.w * wD.y;
            }
            float e0 = __expf(fminf(fmaxf(l0 * invtk, -60.f), 60.f));
            float e1 = __expf(fminf(fmaxf(l1 * invtk, -60.f), 60.f));
            se0 += e0; se1 += e1;
            #pragma unroll
            for (int cc = 0; cc < 8; ++cc) {
                float4 v4 = *(const float4*)&vs[n * 32 + cc * 4];
                acc0[cc*4+0] += e0 * v4.x; acc0[cc*4+1] += e0 * v4.y;
                acc0[cc*4+2] += e0 * v4.z; acc0[cc*4+3] += e0 * v4.w;
                acc1[cc*4+0] += e1 * v4.x; acc1[cc*4+1] += e1 * v4.y;
                acc1[cc*4+2] += e1 * v4.z; acc1[cc*4+3] += e1 * v4.w;
            }
        }
    }

    // deterministic cross-wave reduction; FULLY UNROLLED (compile-time acc idx)
    float* outp = partials + ((size_t)h * 64 + blockIdx.x) * 4224;
    #pragma unroll
    for (int cc = 0; cc < 8; ++cc) {
        __syncthreads();
        #pragma unroll
        for (int ci = 0; ci < 4; ++ci) {
            red[tid * 9 + ci]     = acc0[cc * 4 + ci];
            red[tid * 9 + 4 + ci] = acc1[cc * 4 + ci];
        }
        __syncthreads();
        int d = tid >> 2, ci = tid & 3;
        float s = 0.f;
        #pragma unroll
        for (int pp = 0; pp < 8; ++pp)
            s += red[(pp * 64 + (d >> 1)) * 9 + (d & 1) * 4 + ci];
        outp[d * 32 + cc * 4 + ci] = s;
    }
    __syncthreads();
    red[tid * 9 + 0] = se0;
    red[tid * 9 + 1] = se1;
    __syncthreads();
    if (tid < 128) {
        int d = tid;
        float s = 0.f;
        #pragma unroll
        for (int pp = 0; pp < 8; ++pp)
            s += red[(pp * 64 + (d >> 1)) * 9 + (d & 1)];
        outp[4096 + d] = s;
    }
}

__global__ __launch_bounds__(256) void kv_reduce_kernel(
    const float* __restrict__ partials, float* __restrict__ kvU,
    float* __restrict__ sumexp)
{
    int gid = blockIdx.x * 256 + threadIdx.x;
    if (gid >= 8 * 4224) return;
    int h = gid / 4224, idx = gid % 4224;
    const float* base = partials + (size_t)h * 64 * 4224 + idx;
    float s = 0.f;
    #pragma unroll 8
    for (int c = 0; c < 64; ++c) s += base[(size_t)c * 4224];
    if (idx < 4096) kvU[(size_t)h * 4096 + idx] = s;
    else sumexp[h * 128 + (idx - 4096)] = s;
}

// ---------------------------------------------------------------------------
// qkv2 (unchanged): 2 threads per row, register-resident softmax + PV.
// ---------------------------------------------------------------------------
__global__ __launch_bounds__(256, 3) void qkv2_kernel(
    const float* __restrict__ xm2, const float* __restrict__ wq,
    const float* __restrict__ tq_arr,
    const float* __restrict__ kvU, const float* __restrict__ sumexp,
    float* __restrict__ outD, int layer)
{
    __shared__ __align__(16) float wqs[4096];
    __shared__ __align__(16) float kvs[4096];
    __shared__ __align__(16) float xs[128 * 36];
    __shared__ float ises[128];

    const int tid = threadIdx.x;
    const int h = blockIdx.y;
    const int rl = tid >> 1;
    const int half = tid & 1;
    const int row = blockIdx.x * 128 + rl;

    float tq = fminf(fmaxf(tq_arr[layer * 8 + h], 0.1f), 2.0f);
    float invtq = 1.0f / tq;
    for (int i = tid; i < 4096; i += 256) wqs[i] = wq[i];
    for (int i = tid; i < 4096; i += 256) kvs[i] = kvU[(size_t)h * 4096 + i];
    if (tid < 128) ises[tid] = 1.0f / sumexp[h * 128 + tid];
    {
        const float* src = xm2 + (size_t)h * NP * 32 + (size_t)(blockIdx.x * 128) * 32;
        #pragma unroll
        for (int it = 0; it < 4; ++it) {
            int s = tid + it * 256;
            int r = s >> 3, c4 = s & 7;
            *(float4*)&xs[r * 36 + c4 * 4] = *(const float4*)(src + (size_t)r * 32 + c4 * 4);
        }
    }
    __syncthreads();

    float l[64];
    #pragma unroll
    for (int d = 0; d < 64; ++d) l[d] = 0.f;
    const float* wbase = wqs + half * 64;
    #pragma unroll 4
    for (int j = 0; j < 32; ++j) {
        float xv = xs[rl * 36 + j];
        const float* wr = wbase + j * 128;
        #pragma unroll
        for (int d4 = 0; d4 < 16; ++d4) {
            float4 w4 = *(const float4*)(wr + d4 * 4);
            l[d4*4+0] += xv * w4.x; l[d4*4+1] += xv * w4.y;
            l[d4*4+2] += xv * w4.z; l[d4*4+3] += xv * w4.w;
        }
    }

    float m = l[0];
    #pragma unroll
    for (int d = 1; d < 64; ++d) m = fmaxf(m, l[d]);
    m = fmaxf(m, __shfl_xor(m, 1));
    float s = 0.f;
    #pragma unroll
    for (int d = 0; d < 64; ++d) {
        float e = __expf((l[d] - m) * invtq);
        l[d] = e;
        s += e;
    }
    s += __shfl_xor(s, 1);
    float inv = 1.0f / s;
    #pragma unroll
    for (int d = 0; d < 64; ++d)
        l[d] *= inv * ises[half * 64 + d];

    float out[32];
    #pragma unroll
    for (int c = 0; c < 32; ++c) out[c] = 0.f;
    #pragma unroll
    for (int d = 0; d < 64; ++d) {
        float pd = l[d];
        const float* kvr = kvs + (half * 64 + d) * 32;
        #pragma unroll
        for (int c4 = 0; c4 < 8; ++c4) {
            float4 k4 = *(const float4*)(kvr + c4 * 4);
            out[c4*4+0] += pd * k4.x; out[c4*4+1] += pd * k4.y;
            out[c4*4+2] += pd * k4.z; out[c4*4+3] += pd * k4.w;
        }
    }
    #pragma unroll
    for (int c = 0; c < 32; ++c) out[c] += __shfl_xor(out[c], 1);

    float* op = outD + (size_t)row * 256 + h * 32;
    if (half == 0) {
        float4 o0; o0.x = out[0];  o0.y = out[1];  o0.z = out[2];  o0.w = out[3];
        float4 o1; o1.x = out[4];  o1.y = out[5];  o1.z = out[6];  o1.w = out[7];
        float4 o2; o2.x = out[8];  o2.y = out[9];  o2.z = out[10]; o2.w = out[11];
        float4 o3; o3.x = out[12]; o3.y = out[13]; o3.z = out[14]; o3.w = out[15];
        *(float4*)(op + 0) = o0;  *(float4*)(op + 4) = o1;
        *(float4*)(op + 8) = o2;  *(float4*)(op + 12) = o3;
    } else {
        float4 o0; o0.x = out[16]; o0.y = out[17]; o0.z = out[18]; o0.w = out[19];
        float4 o1; o1.x = out[20]; o1.y = out[21]; o1.z = out[22]; o1.w = out[23];
        float4 o2; o2.x = out[24]; o2.y = out[25]; o2.z = out[26]; o2.w = out[27];
        float4 o3; o3.x = out[28]; o3.y = out[29]; o3.z = out[30]; o3.w = out[31];
        *(float4*)(op + 16) = o0; *(float4*)(op + 20) = o1;
        *(float4*)(op + 24) = o2; *(float4*)(op + 28) = o3;
    }
}

// ---------------------------------------------------------------------------
// head: out[n] = LN(fx[n]; ln3) . head_w + head_b
// ---------------------------------------------------------------------------
__global__ __launch_bounds__(256) void head_kernel(
    const float* __restrict__ fx, const float* __restrict__ g, const float* __restrict__ b,
    const float* __restrict__ hw, const float* __restrict__ hb, float* __restrict__ out)
{
    int lane = threadIdx.x & 63;
    int row = blockIdx.x * 4 + (threadIdx.x >> 6);
    float4 v = *(const float4*)(fx + (size_t)row * 256 + lane * 4);
    float s1 = v.x + v.y + v.z + v.w;
    float s2 = v.x * v.x + v.y * v.y + v.z * v.z + v.w * v.w;
    #pragma unroll
    for (int m = 1; m < 64; m <<= 1) { s1 += __shfl_xor(s1, m); s2 += __shfl_xor(s2, m); }
    float mean = s1 * 0.00390625f;
    float rstd = rsqrtf(fmaxf(s2 * 0.00390625f - mean * mean, 0.f) + 1e-5f);
    float4 gg = *(const float4*)(g + lane * 4);
    float4 bb = *(const float4*)(b + lane * 4);
    float4 w4 = *(const float4*)(hw + lane * 4);
    float d = ((v.x - mean) * rstd * gg.x + bb.x) * w4.x
            + ((v.y - mean) * rstd * gg.y + bb.y) * w4.y
            + ((v.z - mean) * rstd * gg.z + bb.z) * w4.z
            + ((v.w - mean) * rstd * gg.w + bb.w) * w4.w;
    #pragma unroll
    for (int m = 1; m < 64; m <<= 1) d += __shfl_xor(d, m);
    if (lane == 0) out[row] = d + hb[0];
}

extern "C" void kernel_launch(void* const* d_in, const int* in_sizes, int n_in,
                              void* d_out, int out_size, void* d_ws, size_t ws_size,
                              hipStream_t stream)
{
    const float* x      = (const float*)d_in[0];
    const float* pre_w1 = (const float*)d_in[1];
    const float* pre_b1 = (const float*)d_in[2];
    const float* pre_w2 = (const float*)d_in[3];
    const float* pre_b2 = (const float*)d_in[4];
    const float* ph     = (const float*)d_in[5];
    const float* ln1_g  = (const float*)d_in[6];
    const float* ln1_b  = (const float*)d_in[7];
    const float* inp_w  = (const float*)d_in[8];
    const float* inp_b  = (const float*)d_in[9];
    const float* temp_q = (const float*)d_in[10];
    const float* temp_k = (const float*)d_in[11];
    const float* wq     = (const float*)d_in[12];
    const float* wk     = (const float*)d_in[13];
    const float* wv     = (const float*)d_in[14];
    const float* out_w1 = (const float*)d_in[15];
    const float* out_b1 = (const float*)d_in[16];
    const float* out_w2 = (const float*)d_in[17];
    const float* out_b2 = (const float*)d_in[18];
    const float* ln2_g  = (const float*)d_in[19];
    const float* ln2_b  = (const float*)d_in[20];
    const float* mlp_w1 = (const float*)d_in[21];
    const float* mlp_b1 = (const float*)d_in[22];
    const float* mlp_w2 = (const float*)d_in[23];
    const float* mlp_b2 = (const float*)d_in[24];
    const float* ln3_g  = (const float*)d_in[25];
    const float* ln3_b  = (const float*)d_in[26];
    const float* head_w = (const float*)d_in[27];
    const float* head_b = (const float*)d_in[28];
    float* out = (float*)d_out;

    // ws layout (floats): fx | C | Dt | stats | kvU | se | WtPre | WtL
    float* fx = (float*)d_ws;
    float* C  = fx + (size_t)NP * 256;
    float* Dt = C  + (size_t)NP * 256;
    float* st = Dt + (size_t)NP * 256;
    float* kv = st + (size_t)NP * 8;
    float* se = kv + 8 * 4096;
    unsigned short* wtPre = (unsigned short*)(se + 8 * 128);
    unsigned short* wtL   = wtPre + 256 * 512;     // 25 x [256][256]
    float* partials = Dt;                          // alias (Dt dead during kv)

    dim3 bt(256);

    // weight prep (bf16, transposed)
    transpose_bf16_k<<<dim3(16, 8, 1), bt, 0, stream>>>(pre_w2, wtPre, 512);
    transpose_bf16_k<<<dim3(8, 8, 5), bt, 0, stream>>>(inp_w,  wtL +  0 * 65536, 256);
    transpose_bf16_k<<<dim3(8, 8, 5), bt, 0, stream>>>(out_w1, wtL +  5 * 65536, 256);
    transpose_bf16_k<<<dim3(8, 8, 5), bt, 0, stream>>>(out_w2, wtL + 10 * 65536, 256);
    transpose_bf16_k<<<dim3(8, 8, 5), bt, 0, stream>>>(mlp_w1, wtL + 15 * 65536, 256);
    transpose_bf16_k<<<dim3(8, 8, 5), bt, 0, stream>>>(mlp_w2, wtL + 20 * 65536, 256);

    dim3 gg(256, 2);

    // preprocess: fx = GELU(x@pre_w1+pre_b1)@pre_w2 + pre_b2 + placeholder (+stats)
    gemm_mfma<true, false, false, false, true, false><<<gg, bt, 0, stream>>>(
        nullptr, wtPre, pre_b2, ph, fx, nullptr, st, nullptr, nullptr,
        x, pre_w1, pre_b1, 512);

    for (int i = 0; i < 5; ++i) {
        // xm2 = perm( LN(fx;ln1) @ inp_w + inp_b )
        gemm_mfma<false, true, false, false, false, true><<<gg, bt, 0, stream>>>(
            fx, wtL + (size_t)(0 + i) * 65536, inp_b + i * 256, nullptr, C, st, nullptr,
            ln1_g + i * 256, ln1_b + i * 256, nullptr, nullptr, nullptr, 256);
        // kv partials + reduce
        kv3_kernel<<<dim3(64, 8), dim3(512), 0, stream>>>(
            C, wk + (size_t)i * 4096, wv + (size_t)i * 1024, temp_k, partials, i);
        kv_reduce_kernel<<<dim3(132), bt, 0, stream>>>(partials, kv, se);
        // qkv -> Dt [N,256]
        qkv2_kernel<<<dim3(256, 8), bt, 0, stream>>>(C, wq + (size_t)i * 4096, temp_q, kv, se, Dt, i);
        // C = GELU(Dt @ out_w1 + out_b1)
        gemm_mfma<false, false, true, false, false, false><<<gg, bt, 0, stream>>>(
            Dt, wtL + (size_t)(5 + i) * 65536, out_b1 + i * 256, nullptr, C, nullptr, nullptr,
            nullptr, nullptr, nullptr, nullptr, nullptr, 256);
        // fx += C @ out_w2 + out_b2   (+stats for ln2)
        gemm_mfma<false, false, false, true, true, false><<<gg, bt, 0, stream>>>(
            C, wtL + (size_t)(10 + i) * 65536, out_b2 + i * 256, nullptr, fx, nullptr, st,
            nullptr, nullptr, nullptr, nullptr, nullptr, 256);
        // Dt = GELU( LN(fx;ln2) @ mlp_w1 + mlp_b1 )
        gemm_mfma<false, true, true, false, false, false><<<gg, bt, 0, stream>>>(
            fx, wtL + (size_t)(15 + i) * 65536, mlp_b1 + i * 256, nullptr, Dt, st, nullptr,
            ln2_g + i * 256, ln2_b + i * 256, nullptr, nullptr, nullptr, 256);
        // fx += Dt @ mlp_w2 + mlp_b2  (+stats for next ln1)
        gemm_mfma<false, false, false, true, true, false><<<gg, bt, 0, stream>>>(
            Dt, wtL + (size_t)(20 + i) * 65536, mlp_b2 + i * 256, nullptr, fx, nullptr, st,
            nullptr, nullptr, nullptr, nullptr, nullptr, 256);
    }
    head_kernel<<<dim3(NP / 4), bt, 0, stream>>>(fx, ln3_g, ln3_b, head_w, head_b, out);
}

// Round 6
// 2367.200 us; speedup vs baseline: 1.7839x; 1.7839x over previous
//
#include <hip/hip_runtime.h>
#include <hip/hip_bf16.h>
#include <math.h>

constexpr int NP  = 32768;  // mesh points
constexpr int HH  = 8;      // heads

typedef short bf16x8 __attribute__((ext_vector_type(8)));
typedef float f32x4  __attribute__((ext_vector_type(4)));

__device__ __forceinline__ float gelu_f(float x) {
    return 0.5f * x * (1.0f + erff(x * 0.70710678118654752f));
}

__device__ __forceinline__ unsigned short f2bf(float x) {
    union { float f; unsigned u; } v; v.f = x;
    unsigned r = v.u + 0x7fffu + ((v.u >> 16) & 1u);
    return (unsigned short)(r >> 16);
}

// ---------------------------------------------------------------------------
// Weight prep: src [G][K][256] fp32 -> dst [G][256][K] bf16 (transposed)
// ---------------------------------------------------------------------------
__global__ __launch_bounds__(256) void transpose_bf16_k(
    const float* __restrict__ src, unsigned short* __restrict__ dst, int K)
{
    __shared__ float tile[32][33];
    int g = blockIdx.z;
    int k0 = blockIdx.x * 32, c0 = blockIdx.y * 32;
    int tx = threadIdx.x & 31, ty = threadIdx.x >> 5;
    const float* s = src + (size_t)g * K * 256;
    unsigned short* d = dst + (size_t)g * 256 * K;
    #pragma unroll
    for (int rr = 0; rr < 4; ++rr) {
        int r = ty + rr * 8;
        tile[r][tx] = s[(size_t)(k0 + r) * 256 + c0 + tx];
    }
    __syncthreads();
    #pragma unroll
    for (int rr = 0; rr < 4; ++rr) {
        int r = ty + rr * 8;
        d[(size_t)(c0 + r) * K + k0 + tx] = f2bf(tile[tx][r]);
    }
}

// ---------------------------------------------------------------------------
// MFMA GEMM (unchanged): C = epi( A'[N x K] @ W[K x 256] + bias )
// ---------------------------------------------------------------------------
template<bool GENA, bool LNIN, bool DOGELU, bool RESID, bool STATS, bool PERM>
__global__ __launch_bounds__(256) void gemm_mfma(
    const float* __restrict__ A, const unsigned short* __restrict__ Wt,
    const float* __restrict__ bias, const float* __restrict__ bias2,
    float* __restrict__ Cout,
    const float* __restrict__ stats_in, float* __restrict__ stats_out,
    const float* __restrict__ lng, const float* __restrict__ lnb,
    const float* __restrict__ genx, const float* __restrict__ genw1,
    const float* __restrict__ genb1, int K)
{
    __shared__ __align__(16) unsigned short As[128 * 64];
    __shared__ __align__(16) unsigned short Bs[128 * 64];
    __shared__ float rmean[LNIN ? 128 : 1];
    __shared__ float rrstd[LNIN ? 128 : 1];
    __shared__ float w1s[GENA ? 1536 : 1];
    __shared__ float b1s[GENA ? 512 : 1];
    __shared__ float x3s[GENA ? 512 : 1];

    const int tid = threadIdx.x;
    const int rBase = blockIdx.x * 128, cBase = blockIdx.y * 128;

    if constexpr (GENA) {
        for (int i2 = tid; i2 < 1536; i2 += 256) w1s[i2] = genw1[i2];
        for (int i2 = tid; i2 < 512; i2 += 256) b1s[i2] = genb1[i2];
        if (tid < 128) {
            x3s[tid * 4 + 0] = genx[(size_t)(rBase + tid) * 3 + 0];
            x3s[tid * 4 + 1] = genx[(size_t)(rBase + tid) * 3 + 1];
            x3s[tid * 4 + 2] = genx[(size_t)(rBase + tid) * 3 + 2];
        }
        __syncthreads();
    }
    if constexpr (LNIN) {
        if (tid < 128) {
            const float* sp = stats_in + (size_t)(rBase + tid) * 8;
            float4 s0 = *(const float4*)sp;
            float4 s1 = *(const float4*)(sp + 4);
            float mean = (s0.x + s0.z + s1.x + s1.z) * (1.f / 256.f);
            float ex2  = (s0.y + s0.w + s1.y + s1.w) * (1.f / 256.f);
            rmean[tid] = mean;
            rrstd[tid] = rsqrtf(fmaxf(ex2 - mean * mean, 0.f) + 1e-5f);
        }
        __syncthreads();
    }

    f32x4 acc[4][4];
    #pragma unroll
    for (int i = 0; i < 4; ++i)
        #pragma unroll
        for (int j = 0; j < 4; ++j)
            acc[i][j] = (f32x4){0.f, 0.f, 0.f, 0.f};

    const int lane = tid & 63, wid = tid >> 6;
    const int wr = wid >> 1, wc = wid & 1;
    const int lrow = lane & 15, quad = lane >> 4;
    const int srow = tid >> 3;   // 0..31
    const int sch  = tid & 7;    // k-chunk of 8

    for (int kc = 0; kc < K; kc += 64) {
        #pragma unroll
        for (int it = 0; it < 4; ++it) {
            int row = srow + it * 32;
            float v[8];
            if constexpr (GENA) {
                float x0 = x3s[row * 4 + 0], x1 = x3s[row * 4 + 1], x2 = x3s[row * 4 + 2];
                #pragma unroll
                for (int j = 0; j < 8; ++j) {
                    int k = kc + sch * 8 + j;
                    float t = x0 * w1s[k] + x1 * w1s[512 + k] + x2 * w1s[1024 + k] + b1s[k];
                    v[j] = gelu_f(t);
                }
            } else {
                const float* ap = A + (size_t)(rBase + row) * 256 + kc + sch * 8;
                float4 a0 = *(const float4*)ap;
                float4 a1 = *(const float4*)(ap + 4);
                v[0] = a0.x; v[1] = a0.y; v[2] = a0.z; v[3] = a0.w;
                v[4] = a1.x; v[5] = a1.y; v[6] = a1.z; v[7] = a1.w;
                if constexpr (LNIN) {
                    float m = rmean[row], rs = rrstd[row];
                    const float* gp = lng + kc + sch * 8;
                    const float* bp = lnb + kc + sch * 8;
                    float4 g0 = *(const float4*)gp, g1 = *(const float4*)(gp + 4);
                    float4 c0 = *(const float4*)bp, c1 = *(const float4*)(bp + 4);
                    float gg[8] = {g0.x, g0.y, g0.z, g0.w, g1.x, g1.y, g1.z, g1.w};
                    float bb[8] = {c0.x, c0.y, c0.z, c0.w, c1.x, c1.y, c1.z, c1.w};
                    #pragma unroll
                    for (int j = 0; j < 8; ++j) v[j] = (v[j] - m) * rs * gg[j] + bb[j];
                }
            }
            unsigned short pk[8];
            #pragma unroll
            for (int j = 0; j < 8; ++j) pk[j] = f2bf(v[j]);
            *(uint4*)&As[row * 64 + ((sch ^ (row & 7)) << 3)] = *(uint4*)pk;
        }
        #pragma unroll
        for (int it = 0; it < 4; ++it) {
            int n = srow + it * 32;
            uint4 wv_ = *(const uint4*)(Wt + (size_t)(cBase + n) * K + kc + sch * 8);
            *(uint4*)&Bs[n * 64 + ((sch ^ (n & 7)) << 3)] = wv_;
        }
        __syncthreads();
        #pragma unroll
        for (int ks = 0; ks < 2; ++ks) {
            bf16x8 af[4], bfr[4];
            #pragma unroll
            for (int t = 0; t < 4; ++t) {
                int row = wr * 64 + t * 16 + lrow;
                af[t] = *(bf16x8*)&As[row * 64 + (((ks * 4 + quad) ^ (row & 7)) << 3)];
                int n = wc * 64 + t * 16 + lrow;
                bfr[t] = *(bf16x8*)&Bs[n * 64 + (((ks * 4 + quad) ^ (n & 7)) << 3)];
            }
            #pragma unroll
            for (int ti = 0; ti < 4; ++ti)
                #pragma unroll
                for (int tj = 0; tj < 4; ++tj)
                    acc[ti][tj] = __builtin_amdgcn_mfma_f32_16x16x32_bf16(
                        af[ti], bfr[tj], acc[ti][tj], 0, 0, 0);
        }
        __syncthreads();
    }

    float bcol[4];
    #pragma unroll
    for (int tj = 0; tj < 4; ++tj) {
        int gcol = cBase + wc * 64 + tj * 16 + lrow;
        float b = bias[gcol];
        if (bias2) b += bias2[gcol];
        bcol[tj] = b;
    }
    #pragma unroll
    for (int ti = 0; ti < 4; ++ti) {
        #pragma unroll
        for (int r = 0; r < 4; ++r) {
            int grow = rBase + wr * 64 + ti * 16 + quad * 4 + r;
            float vv[4];
            #pragma unroll
            for (int tj = 0; tj < 4; ++tj) {
                float v = acc[ti][tj][r] + bcol[tj];
                if constexpr (DOGELU) v = gelu_f(v);
                vv[tj] = v;
            }
            if constexpr (RESID) {
                #pragma unroll
                for (int tj = 0; tj < 4; ++tj) {
                    int gcol = cBase + wc * 64 + tj * 16 + lrow;
                    vv[tj] += Cout[(size_t)grow * 256 + gcol];
                }
            }
            if constexpr (STATS) {
                float rs = vv[0] + vv[1] + vv[2] + vv[3];
                float rq = vv[0]*vv[0] + vv[1]*vv[1] + vv[2]*vv[2] + vv[3]*vv[3];
                #pragma unroll
                for (int m = 1; m < 16; m <<= 1) {
                    rs += __shfl_xor(rs, m);
                    rq += __shfl_xor(rq, m);
                }
                if (lrow == 0) {
                    stats_out[(size_t)grow * 8 + (blockIdx.y * 2 + wc) * 2 + 0] = rs;
                    stats_out[(size_t)grow * 8 + (blockIdx.y * 2 + wc) * 2 + 1] = rq;
                }
            }
            #pragma unroll
            for (int tj = 0; tj < 4; ++tj) {
                int gcol = cBase + wc * 64 + tj * 16 + lrow;
                if constexpr (PERM)
                    Cout[(size_t)(gcol >> 5) * NP * 32 + (size_t)grow * 32 + (gcol & 31)] = vv[tj];
                else
                    Cout[(size_t)grow * 256 + gcol] = vv[tj];
            }
        }
    }
}

// ---------------------------------------------------------------------------
// kv3: 512 threads; thread (p=tid>>6, dg=tid&63) owns d={2dg,2dg+1} x 32 c.
// R6 fix: __launch_bounds__(512, 2). The previous (512, 4) imposed a 64-VGPR
// cap (VGPR_Count was exactly 64), force-spilling the ~100-float accumulator
// set to scratch (836 MB FETCH / 485 MB WRITE per dispatch). With a >=128
// VGPR budget the accumulators stay in registers.
// partials layout: [h][chunk][4224] = 128*32 kv + 128 sumexp
// ---------------------------------------------------------------------------
__global__ __launch_bounds__(512, 2) void kv3_kernel(
    const float* __restrict__ xm2, const float* __restrict__ wk,
    const float* __restrict__ wv, const float* __restrict__ tk_arr,
    float* __restrict__ partials, int layer)
{
    __shared__ __align__(16) float smem[9216];
    float* xs  = smem;            // [64][32]
    float* vs  = smem + 2048;     // [64][32]
    float* wks = smem + 4096;     // wk linear [32][128]
    float* wvs = smem + 8192;     // [32][32]
    float* red = smem;            // [512][9] alias

    const int tid = threadIdx.x;
    const int h = blockIdx.y;
    const int rowBase = blockIdx.x * 512;
    const int p  = tid >> 6;
    const int dg = tid & 63;

    float tk = fminf(fmaxf(tk_arr[layer * 8 + h], 0.1f), 2.0f);
    float invtk = 1.0f / tk;
    for (int i = tid; i < 4096; i += 512) wks[i] = wk[i];
    for (int i = tid; i < 1024; i += 512) wvs[i] = wv[i];

    float acc0[32], acc1[32];
    #pragma unroll
    for (int c = 0; c < 32; ++c) { acc0[c] = 0.f; acc1[c] = 0.f; }
    float se0 = 0.f, se1 = 0.f;

    const float* src = xm2 + (size_t)h * NP * 32 + (size_t)rowBase * 32;
    const int lr = tid >> 3, lc = (tid & 7) * 4;

    for (int tile = 0; tile < 8; ++tile) {
        __syncthreads();
        *(float4*)&xs[lr * 32 + lc] =
            *(const float4*)(src + (size_t)(tile * 64 + lr) * 32 + lc);
        __syncthreads();
        {
            float a0 = 0.f, a1 = 0.f, a2 = 0.f, a3 = 0.f;
            #pragma unroll
            for (int j = 0; j < 32; ++j) {
                float xv = xs[lr * 32 + j];
                float4 w4 = *(const float4*)&wvs[j * 32 + lc];
                a0 += xv * w4.x; a1 += xv * w4.y; a2 += xv * w4.z; a3 += xv * w4.w;
            }
            float4 o; o.x = a0; o.y = a1; o.z = a2; o.w = a3;
            *(float4*)&vs[lr * 32 + lc] = o;
        }
        __syncthreads();
        #pragma unroll 1
        for (int t = 0; t < 8; ++t) {
            int n = p * 8 + t;
            float l0 = 0.f, l1 = 0.f;
            #pragma unroll
            for (int j4 = 0; j4 < 8; ++j4) {
                float4 x4 = *(const float4*)&xs[n * 32 + j4 * 4];
                float2 wA = *(const float2*)&wks[((j4 * 4 + 0) * 64 + dg) * 2];
                float2 wB = *(const float2*)&wks[((j4 * 4 + 1) * 64 + dg) * 2];
                float2 wC = *(const float2*)&wks[((j4 * 4 + 2) * 64 + dg) * 2];
                float2 wD = *(const float2*)&wks[((j4 * 4 + 3) * 64 + dg) * 2];
                l0 += x4.x * wA.x + x4.y * wB.x + x4.z * wC.x + x4.w * wD.x;
                l1 += x4.x * wA.y + x4.y * wB.y + x4.z * wC.y + x4.w * wD.y;
            }
            float e0 = __expf(fminf(fmaxf(l0 * invtk, -60.f), 60.f));
            float e1 = __expf(fminf(fmaxf(l1 * invtk, -60.f), 60.f));
            se0 += e0; se1 += e1;
            #pragma unroll
            for (int cc = 0; cc < 8; ++cc) {
                float4 v4 = *(const float4*)&vs[n * 32 + cc * 4];
                acc0[cc*4+0] += e0 * v4.x; acc0[cc*4+1] += e0 * v4.y;
                acc0[cc*4+2] += e0 * v4.z; acc0[cc*4+3] += e0 * v4.w;
                acc1[cc*4+0] += e1 * v4.x; acc1[cc*4+1] += e1 * v4.y;
                acc1[cc*4+2] += e1 * v4.z; acc1[cc*4+3] += e1 * v4.w;
            }
        }
    }

    // deterministic cross-wave reduction (fully unrolled, compile-time idx)
    float* outp = partials + ((size_t)h * 64 + blockIdx.x) * 4224;
    #pragma unroll
    for (int cc = 0; cc < 8; ++cc) {
        __syncthreads();
        #pragma unroll
        for (int ci = 0; ci < 4; ++ci) {
            red[tid * 9 + ci]     = acc0[cc * 4 + ci];
            red[tid * 9 + 4 + ci] = acc1[cc * 4 + ci];
        }
        __syncthreads();
        int d = tid >> 2, ci = tid & 3;
        float s = 0.f;
        #pragma unroll
        for (int pp = 0; pp < 8; ++pp)
            s += red[(pp * 64 + (d >> 1)) * 9 + (d & 1) * 4 + ci];
        outp[d * 32 + cc * 4 + ci] = s;
    }
    __syncthreads();
    red[tid * 9 + 0] = se0;
    red[tid * 9 + 1] = se1;
    __syncthreads();
    if (tid < 128) {
        int d = tid;
        float s = 0.f;
        #pragma unroll
        for (int pp = 0; pp < 8; ++pp)
            s += red[(pp * 64 + (d >> 1)) * 9 + (d & 1)];
        outp[4096 + d] = s;
    }
}

__global__ __launch_bounds__(256) void kv_reduce_kernel(
    const float* __restrict__ partials, float* __restrict__ kvU,
    float* __restrict__ sumexp)
{
    int gid = blockIdx.x * 256 + threadIdx.x;
    if (gid >= 8 * 4224) return;
    int h = gid / 4224, idx = gid % 4224;
    const float* base = partials + (size_t)h * 64 * 4224 + idx;
    float s = 0.f;
    #pragma unroll 8
    for (int c = 0; c < 64; ++c) s += base[(size_t)c * 4224];
    if (idx < 4096) kvU[(size_t)h * 4096 + idx] = s;
    else sumexp[h * 128 + (idx - 4096)] = s;
}

// ---------------------------------------------------------------------------
// qkv2 (unchanged): 2 threads per row, register-resident softmax + PV.
// ---------------------------------------------------------------------------
__global__ __launch_bounds__(256, 3) void qkv2_kernel(
    const float* __restrict__ xm2, const float* __restrict__ wq,
    const float* __restrict__ tq_arr,
    const float* __restrict__ kvU, const float* __restrict__ sumexp,
    float* __restrict__ outD, int layer)
{
    __shared__ __align__(16) float wqs[4096];
    __shared__ __align__(16) float kvs[4096];
    __shared__ __align__(16) float xs[128 * 36];
    __shared__ float ises[128];

    const int tid = threadIdx.x;
    const int h = blockIdx.y;
    const int rl = tid >> 1;
    const int half = tid & 1;
    const int row = blockIdx.x * 128 + rl;

    float tq = fminf(fmaxf(tq_arr[layer * 8 + h], 0.1f), 2.0f);
    float invtq = 1.0f / tq;
    for (int i = tid; i < 4096; i += 256) wqs[i] = wq[i];
    for (int i = tid; i < 4096; i += 256) kvs[i] = kvU[(size_t)h * 4096 + i];
    if (tid < 128) ises[tid] = 1.0f / sumexp[h * 128 + tid];
    {
        const float* src = xm2 + (size_t)h * NP * 32 + (size_t)(blockIdx.x * 128) * 32;
        #pragma unroll
        for (int it = 0; it < 4; ++it) {
            int s = tid + it * 256;
            int r = s >> 3, c4 = s & 7;
            *(float4*)&xs[r * 36 + c4 * 4] = *(const float4*)(src + (size_t)r * 32 + c4 * 4);
        }
    }
    __syncthreads();

    float l[64];
    #pragma unroll
    for (int d = 0; d < 64; ++d) l[d] = 0.f;
    const float* wbase = wqs + half * 64;
    #pragma unroll 4
    for (int j = 0; j < 32; ++j) {
        float xv = xs[rl * 36 + j];
        const float* wr = wbase + j * 128;
        #pragma unroll
        for (int d4 = 0; d4 < 16; ++d4) {
            float4 w4 = *(const float4*)(wr + d4 * 4);
            l[d4*4+0] += xv * w4.x; l[d4*4+1] += xv * w4.y;
            l[d4*4+2] += xv * w4.z; l[d4*4+3] += xv * w4.w;
        }
    }

    float m = l[0];
    #pragma unroll
    for (int d = 1; d < 64; ++d) m = fmaxf(m, l[d]);
    m = fmaxf(m, __shfl_xor(m, 1));
    float s = 0.f;
    #pragma unroll
    for (int d = 0; d < 64; ++d) {
        float e = __expf((l[d] - m) * invtq);
        l[d] = e;
        s += e;
    }
    s += __shfl_xor(s, 1);
    float inv = 1.0f / s;
    #pragma unroll
    for (int d = 0; d < 64; ++d)
        l[d] *= inv * ises[half * 64 + d];

    float out[32];
    #pragma unroll
    for (int c = 0; c < 32; ++c) out[c] = 0.f;
    #pragma unroll
    for (int d = 0; d < 64; ++d) {
        float pd = l[d];
        const float* kvr = kvs + (half * 64 + d) * 32;
        #pragma unroll
        for (int c4 = 0; c4 < 8; ++c4) {
            float4 k4 = *(const float4*)(kvr + c4 * 4);
            out[c4*4+0] += pd * k4.x; out[c4*4+1] += pd * k4.y;
            out[c4*4+2] += pd * k4.z; out[c4*4+3] += pd * k4.w;
        }
    }
    #pragma unroll
    for (int c = 0; c < 32; ++c) out[c] += __shfl_xor(out[c], 1);

    float* op = outD + (size_t)row * 256 + h * 32;
    if (half == 0) {
        float4 o0; o0.x = out[0];  o0.y = out[1];  o0.z = out[2];  o0.w = out[3];
        float4 o1; o1.x = out[4];  o1.y = out[5];  o1.z = out[6];  o1.w = out[7];
        float4 o2; o2.x = out[8];  o2.y = out[9];  o2.z = out[10]; o2.w = out[11];
        float4 o3; o3.x = out[12]; o3.y = out[13]; o3.z = out[14]; o3.w = out[15];
        *(float4*)(op + 0) = o0;  *(float4*)(op + 4) = o1;
        *(float4*)(op + 8) = o2;  *(float4*)(op + 12) = o3;
    } else {
        float4 o0; o0.x = out[16]; o0.y = out[17]; o0.z = out[18]; o0.w = out[19];
        float4 o1; o1.x = out[20]; o1.y = out[21]; o1.z = out[22]; o1.w = out[23];
        float4 o2; o2.x = out[24]; o2.y = out[25]; o2.z = out[26]; o2.w = out[27];
        float4 o3; o3.x = out[28]; o3.y = out[29]; o3.z = out[30]; o3.w = out[31];
        *(float4*)(op + 16) = o0; *(float4*)(op + 20) = o1;
        *(float4*)(op + 24) = o2; *(float4*)(op + 28) = o3;
    }
}

// ---------------------------------------------------------------------------
// head: out[n] = LN(fx[n]; ln3) . head_w + head_b
// ---------------------------------------------------------------------------
__global__ __launch_bounds__(256) void head_kernel(
    const float* __restrict__ fx, const float* __restrict__ g, const float* __restrict__ b,
    const float* __restrict__ hw, const float* __restrict__ hb, float* __restrict__ out)
{
    int lane = threadIdx.x & 63;
    int row = blockIdx.x * 4 + (threadIdx.x >> 6);
    float4 v = *(const float4*)(fx + (size_t)row * 256 + lane * 4);
    float s1 = v.x + v.y + v.z + v.w;
    float s2 = v.x * v.x + v.y * v.y + v.z * v.z + v.w * v.w;
    #pragma unroll
    for (int m = 1; m < 64; m <<= 1) { s1 += __shfl_xor(s1, m); s2 += __shfl_xor(s2, m); }
    float mean = s1 * 0.00390625f;
    float rstd = rsqrtf(fmaxf(s2 * 0.00390625f - mean * mean, 0.f) + 1e-5f);
    float4 gg = *(const float4*)(g + lane * 4);
    float4 bb = *(const float4*)(b + lane * 4);
    float4 w4 = *(const float4*)(hw + lane * 4);
    float d = ((v.x - mean) * rstd * gg.x + bb.x) * w4.x
            + ((v.y - mean) * rstd * gg.y + bb.y) * w4.y
            + ((v.z - mean) * rstd * gg.z + bb.z) * w4.z
            + ((v.w - mean) * rstd * gg.w + bb.w) * w4.w;
    #pragma unroll
    for (int m = 1; m < 64; m <<= 1) d += __shfl_xor(d, m);
    if (lane == 0) out[row] = d + hb[0];
}

extern "C" void kernel_launch(void* const* d_in, const int* in_sizes, int n_in,
                              void* d_out, int out_size, void* d_ws, size_t ws_size,
                              hipStream_t stream)
{
    const float* x      = (const float*)d_in[0];
    const float* pre_w1 = (const float*)d_in[1];
    const float* pre_b1 = (const float*)d_in[2];
    const float* pre_w2 = (const float*)d_in[3];
    const float* pre_b2 = (const float*)d_in[4];
    const float* ph     = (const float*)d_in[5];
    const float* ln1_g  = (const float*)d_in[6];
    const float* ln1_b  = (const float*)d_in[7];
    const float* inp_w  = (const float*)d_in[8];
    const float* inp_b  = (const float*)d_in[9];
    const float* temp_q = (const float*)d_in[10];
    const float* temp_k = (const float*)d_in[11];
    const float* wq     = (const float*)d_in[12];
    const float* wk     = (const float*)d_in[13];
    const float* wv     = (const float*)d_in[14];
    const float* out_w1 = (const float*)d_in[15];
    const float* out_b1 = (const float*)d_in[16];
    const float* out_w2 = (const float*)d_in[17];
    const float* out_b2 = (const float*)d_in[18];
    const float* ln2_g  = (const float*)d_in[19];
    const float* ln2_b  = (const float*)d_in[20];
    const float* mlp_w1 = (const float*)d_in[21];
    const float* mlp_b1 = (const float*)d_in[22];
    const float* mlp_w2 = (const float*)d_in[23];
    const float* mlp_b2 = (const float*)d_in[24];
    const float* ln3_g  = (const float*)d_in[25];
    const float* ln3_b  = (const float*)d_in[26];
    const float* head_w = (const float*)d_in[27];
    const float* head_b = (const float*)d_in[28];
    float* out = (float*)d_out;

    // ws layout (floats): fx | C | Dt | stats | kvU | se | WtPre | WtL
    float* fx = (float*)d_ws;
    float* C  = fx + (size_t)NP * 256;
    float* Dt = C  + (size_t)NP * 256;
    float* st = Dt + (size_t)NP * 256;
    float* kv = st + (size_t)NP * 8;
    float* se = kv + 8 * 4096;
    unsigned short* wtPre = (unsigned short*)(se + 8 * 128);
    unsigned short* wtL   = wtPre + 256 * 512;     // 25 x [256][256]
    float* partials = Dt;                          // alias (Dt dead during kv)

    dim3 bt(256);

    // weight prep (bf16, transposed)
    transpose_bf16_k<<<dim3(16, 8, 1), bt, 0, stream>>>(pre_w2, wtPre, 512);
    transpose_bf16_k<<<dim3(8, 8, 5), bt, 0, stream>>>(inp_w,  wtL +  0 * 65536, 256);
    transpose_bf16_k<<<dim3(8, 8, 5), bt, 0, stream>>>(out_w1, wtL +  5 * 65536, 256);
    transpose_bf16_k<<<dim3(8, 8, 5), bt, 0, stream>>>(out_w2, wtL + 10 * 65536, 256);
    transpose_bf16_k<<<dim3(8, 8, 5), bt, 0, stream>>>(mlp_w1, wtL + 15 * 65536, 256);
    transpose_bf16_k<<<dim3(8, 8, 5), bt, 0, stream>>>(mlp_w2, wtL + 20 * 65536, 256);

    dim3 gg(256, 2);

    // preprocess: fx = GELU(x@pre_w1+pre_b1)@pre_w2 + pre_b2 + placeholder (+stats)
    gemm_mfma<true, false, false, false, true, false><<<gg, bt, 0, stream>>>(
        nullptr, wtPre, pre_b2, ph, fx, nullptr, st, nullptr, nullptr,
        x, pre_w1, pre_b1, 512);

    for (int i = 0; i < 5; ++i) {
        // xm2 = perm( LN(fx;ln1) @ inp_w + inp_b )
        gemm_mfma<false, true, false, false, false, true><<<gg, bt, 0, stream>>>(
            fx, wtL + (size_t)(0 + i) * 65536, inp_b + i * 256, nullptr, C, st, nullptr,
            ln1_g + i * 256, ln1_b + i * 256, nullptr, nullptr, nullptr, 256);
        // kv partials + reduce
        kv3_kernel<<<dim3(64, 8), dim3(512), 0, stream>>>(
            C, wk + (size_t)i * 4096, wv + (size_t)i * 1024, temp_k, partials, i);
        kv_reduce_kernel<<<dim3(132), bt, 0, stream>>>(partials, kv, se);
        // qkv -> Dt [N,256]
        qkv2_kernel<<<dim3(256, 8), bt, 0, stream>>>(C, wq + (size_t)i * 4096, temp_q, kv, se, Dt, i);
        // C = GELU(Dt @ out_w1 + out_b1)
        gemm_mfma<false, false, true, false, false, false><<<gg, bt, 0, stream>>>(
            Dt, wtL + (size_t)(5 + i) * 65536, out_b1 + i * 256, nullptr, C, nullptr, nullptr,
            nullptr, nullptr, nullptr, nullptr, nullptr, 256);
        // fx += C @ out_w2 + out_b2   (+stats for ln2)
        gemm_mfma<false, false, false, true, true, false><<<gg, bt, 0, stream>>>(
            C, wtL + (size_t)(10 + i) * 65536, out_b2 + i * 256, nullptr, fx, nullptr, st,
            nullptr, nullptr, nullptr, nullptr, nullptr, 256);
        // Dt = GELU( LN(fx;ln2) @ mlp_w1 + mlp_b1 )
        gemm_mfma<false, true, true, false, false, false><<<gg, bt, 0, stream>>>(
            fx, wtL + (size_t)(15 + i) * 65536, mlp_b1 + i * 256, nullptr, Dt, st, nullptr,
            ln2_g + i * 256, ln2_b + i * 256, nullptr, nullptr, nullptr, 256);
        // fx += Dt @ mlp_w2 + mlp_b2  (+stats for next ln1)
        gemm_mfma<false, false, false, true, true, false><<<gg, bt, 0, stream>>>(
            Dt, wtL + (size_t)(20 + i) * 65536, mlp_b2 + i * 256, nullptr, fx, nullptr, st,
            nullptr, nullptr, nullptr, nullptr, nullptr, 256);
    }
    head_kernel<<<dim3(NP / 4), bt, 0, stream>>>(fx, ln3_g, ln3_b, head_w, head_b, out);
}

// Round 7
// 2271.150 us; speedup vs baseline: 1.8594x; 1.0423x over previous
//
#include <hip/hip_runtime.h>
#include <hip/hip_bf16.h>
#include <math.h>

constexpr int NP  = 32768;  // mesh points
constexpr int HH  = 8;      // heads

typedef short bf16x8 __attribute__((ext_vector_type(8)));
typedef float f32x4  __attribute__((ext_vector_type(4)));

__device__ __forceinline__ float gelu_f(float x) {
    return 0.5f * x * (1.0f + erff(x * 0.70710678118654752f));
}

__device__ __forceinline__ unsigned short f2bf(float x) {
    union { float f; unsigned u; } v; v.f = x;
    unsigned r = v.u + 0x7fffu + ((v.u >> 16) & 1u);
    return (unsigned short)(r >> 16);
}

// ---------------------------------------------------------------------------
// Weight prep: src [G][K][256] fp32 -> dst [G][256][K] bf16 (transposed)
// ---------------------------------------------------------------------------
__global__ __launch_bounds__(256) void transpose_bf16_k(
    const float* __restrict__ src, unsigned short* __restrict__ dst, int K)
{
    __shared__ float tile[32][33];
    int g = blockIdx.z;
    int k0 = blockIdx.x * 32, c0 = blockIdx.y * 32;
    int tx = threadIdx.x & 31, ty = threadIdx.x >> 5;
    const float* s = src + (size_t)g * K * 256;
    unsigned short* d = dst + (size_t)g * 256 * K;
    #pragma unroll
    for (int rr = 0; rr < 4; ++rr) {
        int r = ty + rr * 8;
        tile[r][tx] = s[(size_t)(k0 + r) * 256 + c0 + tx];
    }
    __syncthreads();
    #pragma unroll
    for (int rr = 0; rr < 4; ++rr) {
        int r = ty + rr * 8;
        d[(size_t)(c0 + r) * K + k0 + tx] = f2bf(tile[tx][r]);
    }
}

// ---------------------------------------------------------------------------
// MFMA GEMM (unchanged): C = epi( A'[N x K] @ W[K x 256] + bias )
// ---------------------------------------------------------------------------
template<bool GENA, bool LNIN, bool DOGELU, bool RESID, bool STATS, bool PERM>
__global__ __launch_bounds__(256) void gemm_mfma(
    const float* __restrict__ A, const unsigned short* __restrict__ Wt,
    const float* __restrict__ bias, const float* __restrict__ bias2,
    float* __restrict__ Cout,
    const float* __restrict__ stats_in, float* __restrict__ stats_out,
    const float* __restrict__ lng, const float* __restrict__ lnb,
    const float* __restrict__ genx, const float* __restrict__ genw1,
    const float* __restrict__ genb1, int K)
{
    __shared__ __align__(16) unsigned short As[128 * 64];
    __shared__ __align__(16) unsigned short Bs[128 * 64];
    __shared__ float rmean[LNIN ? 128 : 1];
    __shared__ float rrstd[LNIN ? 128 : 1];
    __shared__ float w1s[GENA ? 1536 : 1];
    __shared__ float b1s[GENA ? 512 : 1];
    __shared__ float x3s[GENA ? 512 : 1];

    const int tid = threadIdx.x;
    const int rBase = blockIdx.x * 128, cBase = blockIdx.y * 128;

    if constexpr (GENA) {
        for (int i2 = tid; i2 < 1536; i2 += 256) w1s[i2] = genw1[i2];
        for (int i2 = tid; i2 < 512; i2 += 256) b1s[i2] = genb1[i2];
        if (tid < 128) {
            x3s[tid * 4 + 0] = genx[(size_t)(rBase + tid) * 3 + 0];
            x3s[tid * 4 + 1] = genx[(size_t)(rBase + tid) * 3 + 1];
            x3s[tid * 4 + 2] = genx[(size_t)(rBase + tid) * 3 + 2];
        }
        __syncthreads();
    }
    if constexpr (LNIN) {
        if (tid < 128) {
            const float* sp = stats_in + (size_t)(rBase + tid) * 8;
            float4 s0 = *(const float4*)sp;
            float4 s1 = *(const float4*)(sp + 4);
            float mean = (s0.x + s0.z + s1.x + s1.z) * (1.f / 256.f);
            float ex2  = (s0.y + s0.w + s1.y + s1.w) * (1.f / 256.f);
            rmean[tid] = mean;
            rrstd[tid] = rsqrtf(fmaxf(ex2 - mean * mean, 0.f) + 1e-5f);
        }
        __syncthreads();
    }

    f32x4 acc[4][4];
    #pragma unroll
    for (int i = 0; i < 4; ++i)
        #pragma unroll
        for (int j = 0; j < 4; ++j)
            acc[i][j] = (f32x4){0.f, 0.f, 0.f, 0.f};

    const int lane = tid & 63, wid = tid >> 6;
    const int wr = wid >> 1, wc = wid & 1;
    const int lrow = lane & 15, quad = lane >> 4;
    const int srow = tid >> 3;   // 0..31
    const int sch  = tid & 7;    // k-chunk of 8

    for (int kc = 0; kc < K; kc += 64) {
        #pragma unroll
        for (int it = 0; it < 4; ++it) {
            int row = srow + it * 32;
            float v[8];
            if constexpr (GENA) {
                float x0 = x3s[row * 4 + 0], x1 = x3s[row * 4 + 1], x2 = x3s[row * 4 + 2];
                #pragma unroll
                for (int j = 0; j < 8; ++j) {
                    int k = kc + sch * 8 + j;
                    float t = x0 * w1s[k] + x1 * w1s[512 + k] + x2 * w1s[1024 + k] + b1s[k];
                    v[j] = gelu_f(t);
                }
            } else {
                const float* ap = A + (size_t)(rBase + row) * 256 + kc + sch * 8;
                float4 a0 = *(const float4*)ap;
                float4 a1 = *(const float4*)(ap + 4);
                v[0] = a0.x; v[1] = a0.y; v[2] = a0.z; v[3] = a0.w;
                v[4] = a1.x; v[5] = a1.y; v[6] = a1.z; v[7] = a1.w;
                if constexpr (LNIN) {
                    float m = rmean[row], rs = rrstd[row];
                    const float* gp = lng + kc + sch * 8;
                    const float* bp = lnb + kc + sch * 8;
                    float4 g0 = *(const float4*)gp, g1 = *(const float4*)(gp + 4);
                    float4 c0 = *(const float4*)bp, c1 = *(const float4*)(bp + 4);
                    float gg[8] = {g0.x, g0.y, g0.z, g0.w, g1.x, g1.y, g1.z, g1.w};
                    float bb[8] = {c0.x, c0.y, c0.z, c0.w, c1.x, c1.y, c1.z, c1.w};
                    #pragma unroll
                    for (int j = 0; j < 8; ++j) v[j] = (v[j] - m) * rs * gg[j] + bb[j];
                }
            }
            unsigned short pk[8];
            #pragma unroll
            for (int j = 0; j < 8; ++j) pk[j] = f2bf(v[j]);
            *(uint4*)&As[row * 64 + ((sch ^ (row & 7)) << 3)] = *(uint4*)pk;
        }
        #pragma unroll
        for (int it = 0; it < 4; ++it) {
            int n = srow + it * 32;
            uint4 wv_ = *(const uint4*)(Wt + (size_t)(cBase + n) * K + kc + sch * 8);
            *(uint4*)&Bs[n * 64 + ((sch ^ (n & 7)) << 3)] = wv_;
        }
        __syncthreads();
        #pragma unroll
        for (int ks = 0; ks < 2; ++ks) {
            bf16x8 af[4], bfr[4];
            #pragma unroll
            for (int t = 0; t < 4; ++t) {
                int row = wr * 64 + t * 16 + lrow;
                af[t] = *(bf16x8*)&As[row * 64 + (((ks * 4 + quad) ^ (row & 7)) << 3)];
                int n = wc * 64 + t * 16 + lrow;
                bfr[t] = *(bf16x8*)&Bs[n * 64 + (((ks * 4 + quad) ^ (n & 7)) << 3)];
            }
            #pragma unroll
            for (int ti = 0; ti < 4; ++ti)
                #pragma unroll
                for (int tj = 0; tj < 4; ++tj)
                    acc[ti][tj] = __builtin_amdgcn_mfma_f32_16x16x32_bf16(
                        af[ti], bfr[tj], acc[ti][tj], 0, 0, 0);
        }
        __syncthreads();
    }

    float bcol[4];
    #pragma unroll
    for (int tj = 0; tj < 4; ++tj) {
        int gcol = cBase + wc * 64 + tj * 16 + lrow;
        float b = bias[gcol];
        if (bias2) b += bias2[gcol];
        bcol[tj] = b;
    }
    #pragma unroll
    for (int ti = 0; ti < 4; ++ti) {
        #pragma unroll
        for (int r = 0; r < 4; ++r) {
            int grow = rBase + wr * 64 + ti * 16 + quad * 4 + r;
            float vv[4];
            #pragma unroll
            for (int tj = 0; tj < 4; ++tj) {
                float v = acc[ti][tj][r] + bcol[tj];
                if constexpr (DOGELU) v = gelu_f(v);
                vv[tj] = v;
            }
            if constexpr (RESID) {
                #pragma unroll
                for (int tj = 0; tj < 4; ++tj) {
                    int gcol = cBase + wc * 64 + tj * 16 + lrow;
                    vv[tj] += Cout[(size_t)grow * 256 + gcol];
                }
            }
            if constexpr (STATS) {
                float rs = vv[0] + vv[1] + vv[2] + vv[3];
                float rq = vv[0]*vv[0] + vv[1]*vv[1] + vv[2]*vv[2] + vv[3]*vv[3];
                #pragma unroll
                for (int m = 1; m < 16; m <<= 1) {
                    rs += __shfl_xor(rs, m);
                    rq += __shfl_xor(rq, m);
                }
                if (lrow == 0) {
                    stats_out[(size_t)grow * 8 + (blockIdx.y * 2 + wc) * 2 + 0] = rs;
                    stats_out[(size_t)grow * 8 + (blockIdx.y * 2 + wc) * 2 + 1] = rq;
                }
            }
            #pragma unroll
            for (int tj = 0; tj < 4; ++tj) {
                int gcol = cBase + wc * 64 + tj * 16 + lrow;
                if constexpr (PERM)
                    Cout[(size_t)(gcol >> 5) * NP * 32 + (size_t)grow * 32 + (gcol & 31)] = vv[tj];
                else
                    Cout[(size_t)grow * 256 + gcol] = vv[tj];
            }
        }
    }
}

// ---------------------------------------------------------------------------
// kv3 (unchanged from R6, working): __launch_bounds__(512, 2) keeps the
// accumulators in VGPRs. Deterministic partials, no atomics.
// partials layout: [h][chunk][4224] = 128*32 kv + 128 sumexp
// ---------------------------------------------------------------------------
__global__ __launch_bounds__(512, 2) void kv3_kernel(
    const float* __restrict__ xm2, const float* __restrict__ wk,
    const float* __restrict__ wv, const float* __restrict__ tk_arr,
    float* __restrict__ partials, int layer)
{
    __shared__ __align__(16) float smem[9216];
    float* xs  = smem;            // [64][32]
    float* vs  = smem + 2048;     // [64][32]
    float* wks = smem + 4096;     // wk linear [32][128]
    float* wvs = smem + 8192;     // [32][32]
    float* red = smem;            // [512][9] alias

    const int tid = threadIdx.x;
    const int h = blockIdx.y;
    const int rowBase = blockIdx.x * 512;
    const int p  = tid >> 6;
    const int dg = tid & 63;

    float tk = fminf(fmaxf(tk_arr[layer * 8 + h], 0.1f), 2.0f);
    float invtk = 1.0f / tk;
    for (int i = tid; i < 4096; i += 512) wks[i] = wk[i];
    for (int i = tid; i < 1024; i += 512) wvs[i] = wv[i];

    float acc0[32], acc1[32];
    #pragma unroll
    for (int c = 0; c < 32; ++c) { acc0[c] = 0.f; acc1[c] = 0.f; }
    float se0 = 0.f, se1 = 0.f;

    const float* src = xm2 + (size_t)h * NP * 32 + (size_t)rowBase * 32;
    const int lr = tid >> 3, lc = (tid & 7) * 4;

    for (int tile = 0; tile < 8; ++tile) {
        __syncthreads();
        *(float4*)&xs[lr * 32 + lc] =
            *(const float4*)(src + (size_t)(tile * 64 + lr) * 32 + lc);
        __syncthreads();
        {
            float a0 = 0.f, a1 = 0.f, a2 = 0.f, a3 = 0.f;
            #pragma unroll
            for (int j = 0; j < 32; ++j) {
                float xv = xs[lr * 32 + j];
                float4 w4 = *(const float4*)&wvs[j * 32 + lc];
                a0 += xv * w4.x; a1 += xv * w4.y; a2 += xv * w4.z; a3 += xv * w4.w;
            }
            float4 o; o.x = a0; o.y = a1; o.z = a2; o.w = a3;
            *(float4*)&vs[lr * 32 + lc] = o;
        }
        __syncthreads();
        #pragma unroll 1
        for (int t = 0; t < 8; ++t) {
            int n = p * 8 + t;
            float l0 = 0.f, l1 = 0.f;
            #pragma unroll
            for (int j4 = 0; j4 < 8; ++j4) {
                float4 x4 = *(const float4*)&xs[n * 32 + j4 * 4];
                float2 wA = *(const float2*)&wks[((j4 * 4 + 0) * 64 + dg) * 2];
                float2 wB = *(const float2*)&wks[((j4 * 4 + 1) * 64 + dg) * 2];
                float2 wC = *(const float2*)&wks[((j4 * 4 + 2) * 64 + dg) * 2];
                float2 wD = *(const float2*)&wks[((j4 * 4 + 3) * 64 + dg) * 2];
                l0 += x4.x * wA.x + x4.y * wB.x + x4.z * wC.x + x4.w * wD.x;
                l1 += x4.x * wA.y + x4.y * wB.y + x4.z * wC.y + x4.w * wD.y;
            }
            float e0 = __expf(fminf(fmaxf(l0 * invtk, -60.f), 60.f));
            float e1 = __expf(fminf(fmaxf(l1 * invtk, -60.f), 60.f));
            se0 += e0; se1 += e1;
            #pragma unroll
            for (int cc = 0; cc < 8; ++cc) {
                float4 v4 = *(const float4*)&vs[n * 32 + cc * 4];
                acc0[cc*4+0] += e0 * v4.x; acc0[cc*4+1] += e0 * v4.y;
                acc0[cc*4+2] += e0 * v4.z; acc0[cc*4+3] += e0 * v4.w;
                acc1[cc*4+0] += e1 * v4.x; acc1[cc*4+1] += e1 * v4.y;
                acc1[cc*4+2] += e1 * v4.z; acc1[cc*4+3] += e1 * v4.w;
            }
        }
    }

    // deterministic cross-wave reduction (fully unrolled, compile-time idx)
    float* outp = partials + ((size_t)h * 64 + blockIdx.x) * 4224;
    #pragma unroll
    for (int cc = 0; cc < 8; ++cc) {
        __syncthreads();
        #pragma unroll
        for (int ci = 0; ci < 4; ++ci) {
            red[tid * 9 + ci]     = acc0[cc * 4 + ci];
            red[tid * 9 + 4 + ci] = acc1[cc * 4 + ci];
        }
        __syncthreads();
        int d = tid >> 2, ci = tid & 3;
        float s = 0.f;
        #pragma unroll
        for (int pp = 0; pp < 8; ++pp)
            s += red[(pp * 64 + (d >> 1)) * 9 + (d & 1) * 4 + ci];
        outp[d * 32 + cc * 4 + ci] = s;
    }
    __syncthreads();
    red[tid * 9 + 0] = se0;
    red[tid * 9 + 1] = se1;
    __syncthreads();
    if (tid < 128) {
        int d = tid;
        float s = 0.f;
        #pragma unroll
        for (int pp = 0; pp < 8; ++pp)
            s += red[(pp * 64 + (d >> 1)) * 9 + (d & 1)];
        outp[4096 + d] = s;
    }
}

__global__ __launch_bounds__(256) void kv_reduce_kernel(
    const float* __restrict__ partials, float* __restrict__ kvU,
    float* __restrict__ sumexp)
{
    int gid = blockIdx.x * 256 + threadIdx.x;
    if (gid >= 8 * 4224) return;
    int h = gid / 4224, idx = gid % 4224;
    const float* base = partials + (size_t)h * 64 * 4224 + idx;
    float s = 0.f;
    #pragma unroll 8
    for (int c = 0; c < 64; ++c) s += base[(size_t)c * 4224];
    if (idx < 4096) kvU[(size_t)h * 4096 + idx] = s;
    else sumexp[h * 128 + (idx - 4096)] = s;
}

// ---------------------------------------------------------------------------
// qkv2: 2 threads per row, register-resident softmax + PV.
// R7 fix: plain __launch_bounds__(256). The R4-added (256,3) min-occupancy
// hint clamped the allocator to 84 VGPR (< ~110 live) and spilled l[] to
// scratch: WRITE_SIZE 112 MB vs the 33.5 MB produced. R3's qkv with a plain
// bound ran at VGPR=140 with WRITE_SIZE exactly 32 MB — proof the hint was
// the cause. Occupancy stays LDS-limited (51.7 KB -> 3 blocks/CU) either way.
// ---------------------------------------------------------------------------
__global__ __launch_bounds__(256) void qkv2_kernel(
    const float* __restrict__ xm2, const float* __restrict__ wq,
    const float* __restrict__ tq_arr,
    const float* __restrict__ kvU, const float* __restrict__ sumexp,
    float* __restrict__ outD, int layer)
{
    __shared__ __align__(16) float wqs[4096];
    __shared__ __align__(16) float kvs[4096];
    __shared__ __align__(16) float xs[128 * 36];
    __shared__ float ises[128];

    const int tid = threadIdx.x;
    const int h = blockIdx.y;
    const int rl = tid >> 1;
    const int half = tid & 1;
    const int row = blockIdx.x * 128 + rl;

    float tq = fminf(fmaxf(tq_arr[layer * 8 + h], 0.1f), 2.0f);
    float invtq = 1.0f / tq;
    for (int i = tid; i < 4096; i += 256) wqs[i] = wq[i];
    for (int i = tid; i < 4096; i += 256) kvs[i] = kvU[(size_t)h * 4096 + i];
    if (tid < 128) ises[tid] = 1.0f / sumexp[h * 128 + tid];
    {
        const float* src = xm2 + (size_t)h * NP * 32 + (size_t)(blockIdx.x * 128) * 32;
        #pragma unroll
        for (int it = 0; it < 4; ++it) {
            int s = tid + it * 256;
            int r = s >> 3, c4 = s & 7;
            *(float4*)&xs[r * 36 + c4 * 4] = *(const float4*)(src + (size_t)r * 32 + c4 * 4);
        }
    }
    __syncthreads();

    float l[64];
    #pragma unroll
    for (int d = 0; d < 64; ++d) l[d] = 0.f;
    const float* wbase = wqs + half * 64;
    #pragma unroll 4
    for (int j = 0; j < 32; ++j) {
        float xv = xs[rl * 36 + j];
        const float* wr = wbase + j * 128;
        #pragma unroll
        for (int d4 = 0; d4 < 16; ++d4) {
            float4 w4 = *(const float4*)(wr + d4 * 4);
            l[d4*4+0] += xv * w4.x; l[d4*4+1] += xv * w4.y;
            l[d4*4+2] += xv * w4.z; l[d4*4+3] += xv * w4.w;
        }
    }

    float m = l[0];
    #pragma unroll
    for (int d = 1; d < 64; ++d) m = fmaxf(m, l[d]);
    m = fmaxf(m, __shfl_xor(m, 1));
    float s = 0.f;
    #pragma unroll
    for (int d = 0; d < 64; ++d) {
        float e = __expf((l[d] - m) * invtq);
        l[d] = e;
        s += e;
    }
    s += __shfl_xor(s, 1);
    float inv = 1.0f / s;
    #pragma unroll
    for (int d = 0; d < 64; ++d)
        l[d] *= inv * ises[half * 64 + d];

    float out[32];
    #pragma unroll
    for (int c = 0; c < 32; ++c) out[c] = 0.f;
    #pragma unroll
    for (int d = 0; d < 64; ++d) {
        float pd = l[d];
        const float* kvr = kvs + (half * 64 + d) * 32;
        #pragma unroll
        for (int c4 = 0; c4 < 8; ++c4) {
            float4 k4 = *(const float4*)(kvr + c4 * 4);
            out[c4*4+0] += pd * k4.x; out[c4*4+1] += pd * k4.y;
            out[c4*4+2] += pd * k4.z; out[c4*4+3] += pd * k4.w;
        }
    }
    #pragma unroll
    for (int c = 0; c < 32; ++c) out[c] += __shfl_xor(out[c], 1);

    float* op = outD + (size_t)row * 256 + h * 32;
    if (half == 0) {
        float4 o0; o0.x = out[0];  o0.y = out[1];  o0.z = out[2];  o0.w = out[3];
        float4 o1; o1.x = out[4];  o1.y = out[5];  o1.z = out[6];  o1.w = out[7];
        float4 o2; o2.x = out[8];  o2.y = out[9];  o2.z = out[10]; o2.w = out[11];
        float4 o3; o3.x = out[12]; o3.y = out[13]; o3.z = out[14]; o3.w = out[15];
        *(float4*)(op + 0) = o0;  *(float4*)(op + 4) = o1;
        *(float4*)(op + 8) = o2;  *(float4*)(op + 12) = o3;
    } else {
        float4 o0; o0.x = out[16]; o0.y = out[17]; o0.z = out[18]; o0.w = out[19];
        float4 o1; o1.x = out[20]; o1.y = out[21]; o1.z = out[22]; o1.w = out[23];
        float4 o2; o2.x = out[24]; o2.y = out[25]; o2.z = out[26]; o2.w = out[27];
        float4 o3; o3.x = out[28]; o3.y = out[29]; o3.z = out[30]; o3.w = out[31];
        *(float4*)(op + 16) = o0; *(float4*)(op + 20) = o1;
        *(float4*)(op + 24) = o2; *(float4*)(op + 28) = o3;
    }
}

// ---------------------------------------------------------------------------
// head: out[n] = LN(fx[n]; ln3) . head_w + head_b
// ---------------------------------------------------------------------------
__global__ __launch_bounds__(256) void head_kernel(
    const float* __restrict__ fx, const float* __restrict__ g, const float* __restrict__ b,
    const float* __restrict__ hw, const float* __restrict__ hb, float* __restrict__ out)
{
    int lane = threadIdx.x & 63;
    int row = blockIdx.x * 4 + (threadIdx.x >> 6);
    float4 v = *(const float4*)(fx + (size_t)row * 256 + lane * 4);
    float s1 = v.x + v.y + v.z + v.w;
    float s2 = v.x * v.x + v.y * v.y + v.z * v.z + v.w * v.w;
    #pragma unroll
    for (int m = 1; m < 64; m <<= 1) { s1 += __shfl_xor(s1, m); s2 += __shfl_xor(s2, m); }
    float mean = s1 * 0.00390625f;
    float rstd = rsqrtf(fmaxf(s2 * 0.00390625f - mean * mean, 0.f) + 1e-5f);
    float4 gg = *(const float4*)(g + lane * 4);
    float4 bb = *(const float4*)(b + lane * 4);
    float4 w4 = *(const float4*)(hw + lane * 4);
    float d = ((v.x - mean) * rstd * gg.x + bb.x) * w4.x
            + ((v.y - mean) * rstd * gg.y + bb.y) * w4.y
            + ((v.z - mean) * rstd * gg.z + bb.z) * w4.z
            + ((v.w - mean) * rstd * gg.w + bb.w) * w4.w;
    #pragma unroll
    for (int m = 1; m < 64; m <<= 1) d += __shfl_xor(d, m);
    if (lane == 0) out[row] = d + hb[0];
}

extern "C" void kernel_launch(void* const* d_in, const int* in_sizes, int n_in,
                              void* d_out, int out_size, void* d_ws, size_t ws_size,
                              hipStream_t stream)
{
    const float* x      = (const float*)d_in[0];
    const float* pre_w1 = (const float*)d_in[1];
    const float* pre_b1 = (const float*)d_in[2];
    const float* pre_w2 = (const float*)d_in[3];
    const float* pre_b2 = (const float*)d_in[4];
    const float* ph     = (const float*)d_in[5];
    const float* ln1_g  = (const float*)d_in[6];
    const float* ln1_b  = (const float*)d_in[7];
    const float* inp_w  = (const float*)d_in[8];
    const float* inp_b  = (const float*)d_in[9];
    const float* temp_q = (const float*)d_in[10];
    const float* temp_k = (const float*)d_in[11];
    const float* wq     = (const float*)d_in[12];
    const float* wk     = (const float*)d_in[13];
    const float* wv     = (const float*)d_in[14];
    const float* out_w1 = (const float*)d_in[15];
    const float* out_b1 = (const float*)d_in[16];
    const float* out_w2 = (const float*)d_in[17];
    const float* out_b2 = (const float*)d_in[18];
    const float* ln2_g  = (const float*)d_in[19];
    const float* ln2_b  = (const float*)d_in[20];
    const float* mlp_w1 = (const float*)d_in[21];
    const float* mlp_b1 = (const float*)d_in[22];
    const float* mlp_w2 = (const float*)d_in[23];
    const float* mlp_b2 = (const float*)d_in[24];
    const float* ln3_g  = (const float*)d_in[25];
    const float* ln3_b  = (const float*)d_in[26];
    const float* head_w = (const float*)d_in[27];
    const float* head_b = (const float*)d_in[28];
    float* out = (float*)d_out;

    // ws layout (floats): fx | C | Dt | stats | kvU | se | WtPre | WtL
    float* fx = (float*)d_ws;
    float* C  = fx + (size_t)NP * 256;
    float* Dt = C  + (size_t)NP * 256;
    float* st = Dt + (size_t)NP * 256;
    float* kv = st + (size_t)NP * 8;
    float* se = kv + 8 * 4096;
    unsigned short* wtPre = (unsigned short*)(se + 8 * 128);
    unsigned short* wtL   = wtPre + 256 * 512;     // 25 x [256][256]
    float* partials = Dt;                          // alias (Dt dead during kv)

    dim3 bt(256);

    // weight prep (bf16, transposed)
    transpose_bf16_k<<<dim3(16, 8, 1), bt, 0, stream>>>(pre_w2, wtPre, 512);
    transpose_bf16_k<<<dim3(8, 8, 5), bt, 0, stream>>>(inp_w,  wtL +  0 * 65536, 256);
    transpose_bf16_k<<<dim3(8, 8, 5), bt, 0, stream>>>(out_w1, wtL +  5 * 65536, 256);
    transpose_bf16_k<<<dim3(8, 8, 5), bt, 0, stream>>>(out_w2, wtL + 10 * 65536, 256);
    transpose_bf16_k<<<dim3(8, 8, 5), bt, 0, stream>>>(mlp_w1, wtL + 15 * 65536, 256);
    transpose_bf16_k<<<dim3(8, 8, 5), bt, 0, stream>>>(mlp_w2, wtL + 20 * 65536, 256);

    dim3 gg(256, 2);

    // preprocess: fx = GELU(x@pre_w1+pre_b1)@pre_w2 + pre_b2 + placeholder (+stats)
    gemm_mfma<true, false, false, false, true, false><<<gg, bt, 0, stream>>>(
        nullptr, wtPre, pre_b2, ph, fx, nullptr, st, nullptr, nullptr,
        x, pre_w1, pre_b1, 512);

    for (int i = 0; i < 5; ++i) {
        // xm2 = perm( LN(fx;ln1) @ inp_w + inp_b )
        gemm_mfma<false, true, false, false, false, true><<<gg, bt, 0, stream>>>(
            fx, wtL + (size_t)(0 + i) * 65536, inp_b + i * 256, nullptr, C, st, nullptr,
            ln1_g + i * 256, ln1_b + i * 256, nullptr, nullptr, nullptr, 256);
        // kv partials + reduce
        kv3_kernel<<<dim3(64, 8), dim3(512), 0, stream>>>(
            C, wk + (size_t)i * 4096, wv + (size_t)i * 1024, temp_k, partials, i);
        kv_reduce_kernel<<<dim3(132), bt, 0, stream>>>(partials, kv, se);
        // qkv -> Dt [N,256]
        qkv2_kernel<<<dim3(256, 8), bt, 0, stream>>>(C, wq + (size_t)i * 4096, temp_q, kv, se, Dt, i);
        // C = GELU(Dt @ out_w1 + out_b1)
        gemm_mfma<false, false, true, false, false, false><<<gg, bt, 0, stream>>>(
            Dt, wtL + (size_t)(5 + i) * 65536, out_b1 + i * 256, nullptr, C, nullptr, nullptr,
            nullptr, nullptr, nullptr, nullptr, nullptr, 256);
        // fx += C @ out_w2 + out_b2   (+stats for ln2)
        gemm_mfma<false, false, false, true, true, false><<<gg, bt, 0, stream>>>(
            C, wtL + (size_t)(10 + i) * 65536, out_b2 + i * 256, nullptr, fx, nullptr, st,
            nullptr, nullptr, nullptr, nullptr, nullptr, 256);
        // Dt = GELU( LN(fx;ln2) @ mlp_w1 + mlp_b1 )
        gemm_mfma<false, true, true, false, false, false><<<gg, bt, 0, stream>>>(
            fx, wtL + (size_t)(15 + i) * 65536, mlp_b1 + i * 256, nullptr, Dt, st, nullptr,
            ln2_g + i * 256, ln2_b + i * 256, nullptr, nullptr, nullptr, 256);
        // fx += Dt @ mlp_w2 + mlp_b2  (+stats for next ln1)
        gemm_mfma<false, false, false, true, true, false><<<gg, bt, 0, stream>>>(
            Dt, wtL + (size_t)(20 + i) * 65536, mlp_b2 + i * 256, nullptr, fx, nullptr, st,
            nullptr, nullptr, nullptr, nullptr, nullptr, 256);
    }
    head_kernel<<<dim3(NP / 4), bt, 0, stream>>>(fx, ln3_g, ln3_b, head_w, head_b, out);
}

// Round 8
// 1690.080 us; speedup vs baseline: 2.4986x; 1.3438x over previous
//
#include <hip/hip_runtime.h>
#include <hip/hip_bf16.h>
#include <math.h>

constexpr int NP  = 32768;  // mesh points
constexpr int HH  = 8;      // heads

typedef short bf16x8 __attribute__((ext_vector_type(8)));
typedef float f32x4  __attribute__((ext_vector_type(4)));

__device__ __forceinline__ float gelu_f(float x) {
    return 0.5f * x * (1.0f + erff(x * 0.70710678118654752f));
}

__device__ __forceinline__ unsigned short f2bf(float x) {
    union { float f; unsigned u; } v; v.f = x;
    unsigned r = v.u + 0x7fffu + ((v.u >> 16) & 1u);
    return (unsigned short)(r >> 16);
}

// ---------------------------------------------------------------------------
// Weight prep: src [G][K][256] fp32 -> dst [G][256][K] bf16 (transposed)
// ---------------------------------------------------------------------------
__global__ __launch_bounds__(256) void transpose_bf16_k(
    const float* __restrict__ src, unsigned short* __restrict__ dst, int K)
{
    __shared__ float tile[32][33];
    int g = blockIdx.z;
    int k0 = blockIdx.x * 32, c0 = blockIdx.y * 32;
    int tx = threadIdx.x & 31, ty = threadIdx.x >> 5;
    const float* s = src + (size_t)g * K * 256;
    unsigned short* d = dst + (size_t)g * 256 * K;
    #pragma unroll
    for (int rr = 0; rr < 4; ++rr) {
        int r = ty + rr * 8;
        tile[r][tx] = s[(size_t)(k0 + r) * 256 + c0 + tx];
    }
    __syncthreads();
    #pragma unroll
    for (int rr = 0; rr < 4; ++rr) {
        int r = ty + rr * 8;
        d[(size_t)(c0 + r) * K + k0 + tx] = f2bf(tile[tx][r]);
    }
}

// ---------------------------------------------------------------------------
// MFMA GEMM (unchanged): C = epi( A'[N x K] @ W[K x 256] + bias )
// ---------------------------------------------------------------------------
template<bool GENA, bool LNIN, bool DOGELU, bool RESID, bool STATS, bool PERM>
__global__ __launch_bounds__(256) void gemm_mfma(
    const float* __restrict__ A, const unsigned short* __restrict__ Wt,
    const float* __restrict__ bias, const float* __restrict__ bias2,
    float* __restrict__ Cout,
    const float* __restrict__ stats_in, float* __restrict__ stats_out,
    const float* __restrict__ lng, const float* __restrict__ lnb,
    const float* __restrict__ genx, const float* __restrict__ genw1,
    const float* __restrict__ genb1, int K)
{
    __shared__ __align__(16) unsigned short As[128 * 64];
    __shared__ __align__(16) unsigned short Bs[128 * 64];
    __shared__ float rmean[LNIN ? 128 : 1];
    __shared__ float rrstd[LNIN ? 128 : 1];
    __shared__ float w1s[GENA ? 1536 : 1];
    __shared__ float b1s[GENA ? 512 : 1];
    __shared__ float x3s[GENA ? 512 : 1];

    const int tid = threadIdx.x;
    const int rBase = blockIdx.x * 128, cBase = blockIdx.y * 128;

    if constexpr (GENA) {
        for (int i2 = tid; i2 < 1536; i2 += 256) w1s[i2] = genw1[i2];
        for (int i2 = tid; i2 < 512; i2 += 256) b1s[i2] = genb1[i2];
        if (tid < 128) {
            x3s[tid * 4 + 0] = genx[(size_t)(rBase + tid) * 3 + 0];
            x3s[tid * 4 + 1] = genx[(size_t)(rBase + tid) * 3 + 1];
            x3s[tid * 4 + 2] = genx[(size_t)(rBase + tid) * 3 + 2];
        }
        __syncthreads();
    }
    if constexpr (LNIN) {
        if (tid < 128) {
            const float* sp = stats_in + (size_t)(rBase + tid) * 8;
            float4 s0 = *(const float4*)sp;
            float4 s1 = *(const float4*)(sp + 4);
            float mean = (s0.x + s0.z + s1.x + s1.z) * (1.f / 256.f);
            float ex2  = (s0.y + s0.w + s1.y + s1.w) * (1.f / 256.f);
            rmean[tid] = mean;
            rrstd[tid] = rsqrtf(fmaxf(ex2 - mean * mean, 0.f) + 1e-5f);
        }
        __syncthreads();
    }

    f32x4 acc[4][4];
    #pragma unroll
    for (int i = 0; i < 4; ++i)
        #pragma unroll
        for (int j = 0; j < 4; ++j)
            acc[i][j] = (f32x4){0.f, 0.f, 0.f, 0.f};

    const int lane = tid & 63, wid = tid >> 6;
    const int wr = wid >> 1, wc = wid & 1;
    const int lrow = lane & 15, quad = lane >> 4;
    const int srow = tid >> 3;   // 0..31
    const int sch  = tid & 7;    // k-chunk of 8

    for (int kc = 0; kc < K; kc += 64) {
        #pragma unroll
        for (int it = 0; it < 4; ++it) {
            int row = srow + it * 32;
            float v[8];
            if constexpr (GENA) {
                float x0 = x3s[row * 4 + 0], x1 = x3s[row * 4 + 1], x2 = x3s[row * 4 + 2];
                #pragma unroll
                for (int j = 0; j < 8; ++j) {
                    int k = kc + sch * 8 + j;
                    float t = x0 * w1s[k] + x1 * w1s[512 + k] + x2 * w1s[1024 + k] + b1s[k];
                    v[j] = gelu_f(t);
                }
            } else {
                const float* ap = A + (size_t)(rBase + row) * 256 + kc + sch * 8;
                float4 a0 = *(const float4*)ap;
                float4 a1 = *(const float4*)(ap + 4);
                v[0] = a0.x; v[1] = a0.y; v[2] = a0.z; v[3] = a0.w;
                v[4] = a1.x; v[5] = a1.y; v[6] = a1.z; v[7] = a1.w;
                if constexpr (LNIN) {
                    float m = rmean[row], rs = rrstd[row];
                    const float* gp = lng + kc + sch * 8;
                    const float* bp = lnb + kc + sch * 8;
                    float4 g0 = *(const float4*)gp, g1 = *(const float4*)(gp + 4);
                    float4 c0 = *(const float4*)bp, c1 = *(const float4*)(bp + 4);
                    float gg[8] = {g0.x, g0.y, g0.z, g0.w, g1.x, g1.y, g1.z, g1.w};
                    float bb[8] = {c0.x, c0.y, c0.z, c0.w, c1.x, c1.y, c1.z, c1.w};
                    #pragma unroll
                    for (int j = 0; j < 8; ++j) v[j] = (v[j] - m) * rs * gg[j] + bb[j];
                }
            }
            unsigned short pk[8];
            #pragma unroll
            for (int j = 0; j < 8; ++j) pk[j] = f2bf(v[j]);
            *(uint4*)&As[row * 64 + ((sch ^ (row & 7)) << 3)] = *(uint4*)pk;
        }
        #pragma unroll
        for (int it = 0; it < 4; ++it) {
            int n = srow + it * 32;
            uint4 wv_ = *(const uint4*)(Wt + (size_t)(cBase + n) * K + kc + sch * 8);
            *(uint4*)&Bs[n * 64 + ((sch ^ (n & 7)) << 3)] = wv_;
        }
        __syncthreads();
        #pragma unroll
        for (int ks = 0; ks < 2; ++ks) {
            bf16x8 af[4], bfr[4];
            #pragma unroll
            for (int t = 0; t < 4; ++t) {
                int row = wr * 64 + t * 16 + lrow;
                af[t] = *(bf16x8*)&As[row * 64 + (((ks * 4 + quad) ^ (row & 7)) << 3)];
                int n = wc * 64 + t * 16 + lrow;
                bfr[t] = *(bf16x8*)&Bs[n * 64 + (((ks * 4 + quad) ^ (n & 7)) << 3)];
            }
            #pragma unroll
            for (int ti = 0; ti < 4; ++ti)
                #pragma unroll
                for (int tj = 0; tj < 4; ++tj)
                    acc[ti][tj] = __builtin_amdgcn_mfma_f32_16x16x32_bf16(
                        af[ti], bfr[tj], acc[ti][tj], 0, 0, 0);
        }
        __syncthreads();
    }

    float bcol[4];
    #pragma unroll
    for (int tj = 0; tj < 4; ++tj) {
        int gcol = cBase + wc * 64 + tj * 16 + lrow;
        float b = bias[gcol];
        if (bias2) b += bias2[gcol];
        bcol[tj] = b;
    }
    #pragma unroll
    for (int ti = 0; ti < 4; ++ti) {
        #pragma unroll
        for (int r = 0; r < 4; ++r) {
            int grow = rBase + wr * 64 + ti * 16 + quad * 4 + r;
            float vv[4];
            #pragma unroll
            for (int tj = 0; tj < 4; ++tj) {
                float v = acc[ti][tj][r] + bcol[tj];
                if constexpr (DOGELU) v = gelu_f(v);
                vv[tj] = v;
            }
            if constexpr (RESID) {
                #pragma unroll
                for (int tj = 0; tj < 4; ++tj) {
                    int gcol = cBase + wc * 64 + tj * 16 + lrow;
                    vv[tj] += Cout[(size_t)grow * 256 + gcol];
                }
            }
            if constexpr (STATS) {
                float rs = vv[0] + vv[1] + vv[2] + vv[3];
                float rq = vv[0]*vv[0] + vv[1]*vv[1] + vv[2]*vv[2] + vv[3]*vv[3];
                #pragma unroll
                for (int m = 1; m < 16; m <<= 1) {
                    rs += __shfl_xor(rs, m);
                    rq += __shfl_xor(rq, m);
                }
                if (lrow == 0) {
                    stats_out[(size_t)grow * 8 + (blockIdx.y * 2 + wc) * 2 + 0] = rs;
                    stats_out[(size_t)grow * 8 + (blockIdx.y * 2 + wc) * 2 + 1] = rq;
                }
            }
            #pragma unroll
            for (int tj = 0; tj < 4; ++tj) {
                int gcol = cBase + wc * 64 + tj * 16 + lrow;
                if constexpr (PERM)
                    Cout[(size_t)(gcol >> 5) * NP * 32 + (size_t)grow * 32 + (gcol & 31)] = vv[tj];
                else
                    Cout[(size_t)grow * 256 + gcol] = vv[tj];
            }
        }
    }
}

// ---------------------------------------------------------------------------
// kv3 (unchanged from R6, working): __launch_bounds__(512, 2) keeps the
// accumulators in VGPRs. Deterministic partials, no atomics.
// partials layout: [h][chunk][4224] = 128*32 kv + 128 sumexp
// ---------------------------------------------------------------------------
__global__ __launch_bounds__(512, 2) void kv3_kernel(
    const float* __restrict__ xm2, const float* __restrict__ wk,
    const float* __restrict__ wv, const float* __restrict__ tk_arr,
    float* __restrict__ partials, int layer)
{
    __shared__ __align__(16) float smem[9216];
    float* xs  = smem;            // [64][32]
    float* vs  = smem + 2048;     // [64][32]
    float* wks = smem + 4096;     // wk linear [32][128]
    float* wvs = smem + 8192;     // [32][32]
    float* red = smem;            // [512][9] alias

    const int tid = threadIdx.x;
    const int h = blockIdx.y;
    const int rowBase = blockIdx.x * 512;
    const int p  = tid >> 6;
    const int dg = tid & 63;

    float tk = fminf(fmaxf(tk_arr[layer * 8 + h], 0.1f), 2.0f);
    float invtk = 1.0f / tk;
    for (int i = tid; i < 4096; i += 512) wks[i] = wk[i];
    for (int i = tid; i < 1024; i += 512) wvs[i] = wv[i];

    float acc0[32], acc1[32];
    #pragma unroll
    for (int c = 0; c < 32; ++c) { acc0[c] = 0.f; acc1[c] = 0.f; }
    float se0 = 0.f, se1 = 0.f;

    const float* src = xm2 + (size_t)h * NP * 32 + (size_t)rowBase * 32;
    const int lr = tid >> 3, lc = (tid & 7) * 4;

    for (int tile = 0; tile < 8; ++tile) {
        __syncthreads();
        *(float4*)&xs[lr * 32 + lc] =
            *(const float4*)(src + (size_t)(tile * 64 + lr) * 32 + lc);
        __syncthreads();
        {
            float a0 = 0.f, a1 = 0.f, a2 = 0.f, a3 = 0.f;
            #pragma unroll
            for (int j = 0; j < 32; ++j) {
                float xv = xs[lr * 32 + j];
                float4 w4 = *(const float4*)&wvs[j * 32 + lc];
                a0 += xv * w4.x; a1 += xv * w4.y; a2 += xv * w4.z; a3 += xv * w4.w;
            }
            float4 o; o.x = a0; o.y = a1; o.z = a2; o.w = a3;
            *(float4*)&vs[lr * 32 + lc] = o;
        }
        __syncthreads();
        #pragma unroll 1
        for (int t = 0; t < 8; ++t) {
            int n = p * 8 + t;
            float l0 = 0.f, l1 = 0.f;
            #pragma unroll
            for (int j4 = 0; j4 < 8; ++j4) {
                float4 x4 = *(const float4*)&xs[n * 32 + j4 * 4];
                float2 wA = *(const float2*)&wks[((j4 * 4 + 0) * 64 + dg) * 2];
                float2 wB = *(const float2*)&wks[((j4 * 4 + 1) * 64 + dg) * 2];
                float2 wC = *(const float2*)&wks[((j4 * 4 + 2) * 64 + dg) * 2];
                float2 wD = *(const float2*)&wks[((j4 * 4 + 3) * 64 + dg) * 2];
                l0 += x4.x * wA.x + x4.y * wB.x + x4.z * wC.x + x4.w * wD.x;
                l1 += x4.x * wA.y + x4.y * wB.y + x4.z * wC.y + x4.w * wD.y;
            }
            float e0 = __expf(fminf(fmaxf(l0 * invtk, -60.f), 60.f));
            float e1 = __expf(fminf(fmaxf(l1 * invtk, -60.f), 60.f));
            se0 += e0; se1 += e1;
            #pragma unroll
            for (int cc = 0; cc < 8; ++cc) {
                float4 v4 = *(const float4*)&vs[n * 32 + cc * 4];
                acc0[cc*4+0] += e0 * v4.x; acc0[cc*4+1] += e0 * v4.y;
                acc0[cc*4+2] += e0 * v4.z; acc0[cc*4+3] += e0 * v4.w;
                acc1[cc*4+0] += e1 * v4.x; acc1[cc*4+1] += e1 * v4.y;
                acc1[cc*4+2] += e1 * v4.z; acc1[cc*4+3] += e1 * v4.w;
            }
        }
    }

    // deterministic cross-wave reduction (fully unrolled, compile-time idx)
    float* outp = partials + ((size_t)h * 64 + blockIdx.x) * 4224;
    #pragma unroll
    for (int cc = 0; cc < 8; ++cc) {
        __syncthreads();
        #pragma unroll
        for (int ci = 0; ci < 4; ++ci) {
            red[tid * 9 + ci]     = acc0[cc * 4 + ci];
            red[tid * 9 + 4 + ci] = acc1[cc * 4 + ci];
        }
        __syncthreads();
        int d = tid >> 2, ci = tid & 3;
        float s = 0.f;
        #pragma unroll
        for (int pp = 0; pp < 8; ++pp)
            s += red[(pp * 64 + (d >> 1)) * 9 + (d & 1) * 4 + ci];
        outp[d * 32 + cc * 4 + ci] = s;
    }
    __syncthreads();
    red[tid * 9 + 0] = se0;
    red[tid * 9 + 1] = se1;
    __syncthreads();
    if (tid < 128) {
        int d = tid;
        float s = 0.f;
        #pragma unroll
        for (int pp = 0; pp < 8; ++pp)
            s += red[(pp * 64 + (d >> 1)) * 9 + (d & 1)];
        outp[4096 + d] = s;
    }
}

__global__ __launch_bounds__(256) void kv_reduce_kernel(
    const float* __restrict__ partials, float* __restrict__ kvU,
    float* __restrict__ sumexp)
{
    int gid = blockIdx.x * 256 + threadIdx.x;
    if (gid >= 8 * 4224) return;
    int h = gid / 4224, idx = gid % 4224;
    const float* base = partials + (size_t)h * 64 * 4224 + idx;
    float s = 0.f;
    #pragma unroll 8
    for (int c = 0; c < 64; ++c) s += base[(size_t)c * 4224];
    if (idx < 4096) kvU[(size_t)h * 4096 + idx] = s;
    else sumexp[h * 128 + (idx - 4096)] = s;
}

// ---------------------------------------------------------------------------
// qkv3 (R8): balanced 8x8 register tiling. Thread (rt=tid>>4, dt=tid&15)
// owns rows rt*8..+7 x d's dt*8..+7. LDS traffic cut 8x vs qkv2 (each wq/kv
// float4 feeds 8 FMAs; each xs float4 feeds 32). All LDS layouts XOR-swizzle
// the float4-chunk index by ((owner>>3)&7) so distinct-address reads are
// <=2-way (free, m136). Softmax over d via shfl_xor{1,2,4,8} in the 16-lane
// dt-group; PV reduced with a 4-step reduce-scatter (compile-time register
// indices only), each lane ending with one float4 to store.
// ---------------------------------------------------------------------------
__global__ __launch_bounds__(256) void qkv3_kernel(
    const float* __restrict__ xm2, const float* __restrict__ wq,
    const float* __restrict__ tq_arr,
    const float* __restrict__ kvU, const float* __restrict__ sumexp,
    float* __restrict__ outD, int layer)
{
    __shared__ __align__(16) float xsw[4096];   // [128 rows][32], chunk-swizzled
    __shared__ __align__(16) float wqs[4096];   // [32 k][128 d], chunk-swizzled
    __shared__ __align__(16) float kvs[4096];   // [128 d][32 c], chunk-swizzled
    __shared__ float ises[128];

    const int tid = threadIdx.x;
    const int h = blockIdx.y;
    const int rowBase = blockIdx.x * 128;
    const int rt = tid >> 4;      // row-tile 0..15
    const int dt = tid & 15;      // d-tile 0..15

    float tq = fminf(fmaxf(tq_arr[layer * 8 + h], 0.1f), 2.0f);
    float invtq = 1.0f / tq;

    if (tid < 128) ises[tid] = 1.0f / sumexp[h * 128 + tid];
    // wq stage: element (k,d); chunk c4=d>>2 stored at c4^((c4>>1)&7)
    #pragma unroll
    for (int it = 0; it < 4; ++it) {
        int i4 = tid + it * 256;            // 1024 float4 slots
        int k = i4 >> 5, c4 = i4 & 31;
        float4 v = *(const float4*)(wq + (size_t)k * 128 + c4 * 4);
        int c4s = c4 ^ ((c4 >> 1) & 7);
        *(float4*)&wqs[k * 128 + c4s * 4] = v;
    }
    // kv stage: element (d,c); chunk c4=c>>2 stored at c4^((d>>3)&7)
    {
        const float* kvsrc = kvU + (size_t)h * 4096;
        #pragma unroll
        for (int it = 0; it < 4; ++it) {
            int i4 = tid + it * 256;
            int d = i4 >> 3, c4 = i4 & 7;
            float4 v = *(const float4*)(kvsrc + (size_t)d * 32 + c4 * 4);
            int c4s = c4 ^ ((d >> 3) & 7);
            *(float4*)&kvs[d * 32 + c4s * 4] = v;
        }
    }
    // xs stage: row r chunk j4 stored at j4^((r>>3)&7)
    {
        const float* src = xm2 + (size_t)h * NP * 32 + (size_t)rowBase * 32;
        #pragma unroll
        for (int it = 0; it < 4; ++it) {
            int s = tid + it * 256;
            int r = s >> 3, j4 = s & 7;
            float4 v = *(const float4*)(src + (size_t)r * 32 + j4 * 4);
            *(float4*)&xsw[r * 32 + ((j4 ^ ((r >> 3) & 7)) << 2)] = v;
        }
    }
    __syncthreads();

    const int swr = rt & 7;
    const int swd = dt & 7;

    // ---- phase 1: q logits l[8 rows][8 d] ----
    float l[8][8];
    #pragma unroll
    for (int i = 0; i < 8; ++i)
        #pragma unroll
        for (int jd = 0; jd < 8; ++jd) l[i][jd] = 0.f;

    const int cA = (dt * 2)     ^ swd;   // swizzled chunk for d = dt*8..+3
    const int cB = (dt * 2 + 1) ^ swd;   // swizzled chunk for d = dt*8+4..+7
    #pragma unroll
    for (int j4 = 0; j4 < 8; ++j4) {
        float4 xv[8];
        #pragma unroll
        for (int i = 0; i < 8; ++i)
            xv[i] = *(const float4*)&xsw[(rt * 8 + i) * 32 + ((j4 ^ swr) << 2)];
        #pragma unroll
        for (int kk = 0; kk < 4; ++kk) {
            int k = j4 * 4 + kk;
            float4 wa = *(const float4*)&wqs[k * 128 + cA * 4];
            float4 wb = *(const float4*)&wqs[k * 128 + cB * 4];
            #pragma unroll
            for (int i = 0; i < 8; ++i) {
                float xx = (kk == 0) ? xv[i].x : (kk == 1) ? xv[i].y
                         : (kk == 2) ? xv[i].z : xv[i].w;
                l[i][0] += xx * wa.x; l[i][1] += xx * wa.y;
                l[i][2] += xx * wa.z; l[i][3] += xx * wa.w;
                l[i][4] += xx * wb.x; l[i][5] += xx * wb.y;
                l[i][6] += xx * wb.z; l[i][7] += xx * wb.w;
            }
        }
    }

    // ---- softmax over d (128 = 16 dt-lanes x 8 regs), then x ises ----
    float isr[8];
    #pragma unroll
    for (int jd = 0; jd < 8; ++jd) isr[jd] = ises[dt * 8 + jd];
    #pragma unroll
    for (int i = 0; i < 8; ++i) {
        float m = l[i][0];
        #pragma unroll
        for (int jd = 1; jd < 8; ++jd) m = fmaxf(m, l[i][jd]);
        m = fmaxf(m, __shfl_xor(m, 1));
        m = fmaxf(m, __shfl_xor(m, 2));
        m = fmaxf(m, __shfl_xor(m, 4));
        m = fmaxf(m, __shfl_xor(m, 8));
        float s = 0.f;
        #pragma unroll
        for (int jd = 0; jd < 8; ++jd) {
            float e = __expf((l[i][jd] - m) * invtq);
            l[i][jd] = e;
            s += e;
        }
        s += __shfl_xor(s, 1);
        s += __shfl_xor(s, 2);
        s += __shfl_xor(s, 4);
        s += __shfl_xor(s, 8);
        float inv = 1.0f / s;
        #pragma unroll
        for (int jd = 0; jd < 8; ++jd) l[i][jd] *= inv * isr[jd];
    }

    // ---- phase 2: PV with reduce-scatter over dt ----
    const int b0 = dt & 1, b1 = (dt >> 1) & 1, b2 = (dt >> 2) & 1, b3 = (dt >> 3) & 1;
    #pragma unroll
    for (int chunk = 0; chunk < 4; ++chunk) {
        float o[8][8];
        #pragma unroll
        for (int i = 0; i < 8; ++i)
            #pragma unroll
            for (int c = 0; c < 8; ++c) o[i][c] = 0.f;
        const int kA = (chunk * 2)     ^ swd;
        const int kB = (chunk * 2 + 1) ^ swd;
        #pragma unroll
        for (int jd = 0; jd < 8; ++jd) {
            int d = dt * 8 + jd;
            float4 ka = *(const float4*)&kvs[d * 32 + kA * 4];
            float4 kb = *(const float4*)&kvs[d * 32 + kB * 4];
            #pragma unroll
            for (int i = 0; i < 8; ++i) {
                float p = l[i][jd];
                o[i][0] += p * ka.x; o[i][1] += p * ka.y;
                o[i][2] += p * ka.z; o[i][3] += p * ka.w;
                o[i][4] += p * kb.x; o[i][5] += p * kb.y;
                o[i][6] += p * kb.z; o[i][7] += p * kb.w;
            }
        }
        // step 1 (xor 1): split rows 0-3 / 4-7 by b0
        float t1[4][8];
        #pragma unroll
        for (int i = 0; i < 4; ++i)
            #pragma unroll
            for (int c = 0; c < 8; ++c) {
                float keep = b0 ? o[i + 4][c] : o[i][c];
                float send = b0 ? o[i][c] : o[i + 4][c];
                t1[i][c] = keep + __shfl_xor(send, 1);
            }
        // step 2 (xor 2): split rows pairs by b1
        float t2[2][8];
        #pragma unroll
        for (int i = 0; i < 2; ++i)
            #pragma unroll
            for (int c = 0; c < 8; ++c) {
                float keep = b1 ? t1[i + 2][c] : t1[i][c];
                float send = b1 ? t1[i][c] : t1[i + 2][c];
                t2[i][c] = keep + __shfl_xor(send, 2);
            }
        // step 3 (xor 4): split c halves by b2
        float t3[2][4];
        #pragma unroll
        for (int i = 0; i < 2; ++i)
            #pragma unroll
            for (int c = 0; c < 4; ++c) {
                float keep = b2 ? t2[i][c + 4] : t2[i][c];
                float send = b2 ? t2[i][c] : t2[i][c + 4];
                t3[i][c] = keep + __shfl_xor(send, 4);
            }
        // step 4 (xor 8): split remaining row pair by b3
        float t4[4];
        #pragma unroll
        for (int c = 0; c < 4; ++c) {
            float keep = b3 ? t3[1][c] : t3[0][c];
            float send = b3 ? t3[0][c] : t3[1][c];
            t4[c] = keep + __shfl_xor(send, 8);
        }
        int row = rt * 8 + b0 * 4 + b1 * 2 + b3;
        float4 ov; ov.x = t4[0]; ov.y = t4[1]; ov.z = t4[2]; ov.w = t4[3];
        *(float4*)(outD + (size_t)(rowBase + row) * 256 + h * 32 + chunk * 8 + b2 * 4) = ov;
    }
}

// ---------------------------------------------------------------------------
// head: out[n] = LN(fx[n]; ln3) . head_w + head_b
// ---------------------------------------------------------------------------
__global__ __launch_bounds__(256) void head_kernel(
    const float* __restrict__ fx, const float* __restrict__ g, const float* __restrict__ b,
    const float* __restrict__ hw, const float* __restrict__ hb, float* __restrict__ out)
{
    int lane = threadIdx.x & 63;
    int row = blockIdx.x * 4 + (threadIdx.x >> 6);
    float4 v = *(const float4*)(fx + (size_t)row * 256 + lane * 4);
    float s1 = v.x + v.y + v.z + v.w;
    float s2 = v.x * v.x + v.y * v.y + v.z * v.z + v.w * v.w;
    #pragma unroll
    for (int m = 1; m < 64; m <<= 1) { s1 += __shfl_xor(s1, m); s2 += __shfl_xor(s2, m); }
    float mean = s1 * 0.00390625f;
    float rstd = rsqrtf(fmaxf(s2 * 0.00390625f - mean * mean, 0.f) + 1e-5f);
    float4 gg = *(const float4*)(g + lane * 4);
    float4 bb = *(const float4*)(b + lane * 4);
    float4 w4 = *(const float4*)(hw + lane * 4);
    float d = ((v.x - mean) * rstd * gg.x + bb.x) * w4.x
            + ((v.y - mean) * rstd * gg.y + bb.y) * w4.y
            + ((v.z - mean) * rstd * gg.z + bb.z) * w4.z
            + ((v.w - mean) * rstd * gg.w + bb.w) * w4.w;
    #pragma unroll
    for (int m = 1; m < 64; m <<= 1) d += __shfl_xor(d, m);
    if (lane == 0) out[row] = d + hb[0];
}

extern "C" void kernel_launch(void* const* d_in, const int* in_sizes, int n_in,
                              void* d_out, int out_size, void* d_ws, size_t ws_size,
                              hipStream_t stream)
{
    const float* x      = (const float*)d_in[0];
    const float* pre_w1 = (const float*)d_in[1];
    const float* pre_b1 = (const float*)d_in[2];
    const float* pre_w2 = (const float*)d_in[3];
    const float* pre_b2 = (const float*)d_in[4];
    const float* ph     = (const float*)d_in[5];
    const float* ln1_g  = (const float*)d_in[6];
    const float* ln1_b  = (const float*)d_in[7];
    const float* inp_w  = (const float*)d_in[8];
    const float* inp_b  = (const float*)d_in[9];
    const float* temp_q = (const float*)d_in[10];
    const float* temp_k = (const float*)d_in[11];
    const float* wq     = (const float*)d_in[12];
    const float* wk     = (const float*)d_in[13];
    const float* wv     = (const float*)d_in[14];
    const float* out_w1 = (const float*)d_in[15];
    const float* out_b1 = (const float*)d_in[16];
    const float* out_w2 = (const float*)d_in[17];
    const float* out_b2 = (const float*)d_in[18];
    const float* ln2_g  = (const float*)d_in[19];
    const float* ln2_b  = (const float*)d_in[20];
    const float* mlp_w1 = (const float*)d_in[21];
    const float* mlp_b1 = (const float*)d_in[22];
    const float* mlp_w2 = (const float*)d_in[23];
    const float* mlp_b2 = (const float*)d_in[24];
    const float* ln3_g  = (const float*)d_in[25];
    const float* ln3_b  = (const float*)d_in[26];
    const float* head_w = (const float*)d_in[27];
    const float* head_b = (const float*)d_in[28];
    float* out = (float*)d_out;

    // ws layout (floats): fx | C | Dt | stats | kvU | se | WtPre | WtL
    float* fx = (float*)d_ws;
    float* C  = fx + (size_t)NP * 256;
    float* Dt = C  + (size_t)NP * 256;
    float* st = Dt + (size_t)NP * 256;
    float* kv = st + (size_t)NP * 8;
    float* se = kv + 8 * 4096;
    unsigned short* wtPre = (unsigned short*)(se + 8 * 128);
    unsigned short* wtL   = wtPre + 256 * 512;     // 25 x [256][256]
    float* partials = Dt;                          // alias (Dt dead during kv)

    dim3 bt(256);

    // weight prep (bf16, transposed)
    transpose_bf16_k<<<dim3(16, 8, 1), bt, 0, stream>>>(pre_w2, wtPre, 512);
    transpose_bf16_k<<<dim3(8, 8, 5), bt, 0, stream>>>(inp_w,  wtL +  0 * 65536, 256);
    transpose_bf16_k<<<dim3(8, 8, 5), bt, 0, stream>>>(out_w1, wtL +  5 * 65536, 256);
    transpose_bf16_k<<<dim3(8, 8, 5), bt, 0, stream>>>(out_w2, wtL + 10 * 65536, 256);
    transpose_bf16_k<<<dim3(8, 8, 5), bt, 0, stream>>>(mlp_w1, wtL + 15 * 65536, 256);
    transpose_bf16_k<<<dim3(8, 8, 5), bt, 0, stream>>>(mlp_w2, wtL + 20 * 65536, 256);

    dim3 gg(256, 2);

    // preprocess: fx = GELU(x@pre_w1+pre_b1)@pre_w2 + pre_b2 + placeholder (+stats)
    gemm_mfma<true, false, false, false, true, false><<<gg, bt, 0, stream>>>(
        nullptr, wtPre, pre_b2, ph, fx, nullptr, st, nullptr, nullptr,
        x, pre_w1, pre_b1, 512);

    for (int i = 0; i < 5; ++i) {
        // xm2 = perm( LN(fx;ln1) @ inp_w + inp_b )
        gemm_mfma<false, true, false, false, false, true><<<gg, bt, 0, stream>>>(
            fx, wtL + (size_t)(0 + i) * 65536, inp_b + i * 256, nullptr, C, st, nullptr,
            ln1_g + i * 256, ln1_b + i * 256, nullptr, nullptr, nullptr, 256);
        // kv partials + reduce
        kv3_kernel<<<dim3(64, 8), dim3(512), 0, stream>>>(
            C, wk + (size_t)i * 4096, wv + (size_t)i * 1024, temp_k, partials, i);
        kv_reduce_kernel<<<dim3(132), bt, 0, stream>>>(partials, kv, se);
        // qkv -> Dt [N,256]
        qkv3_kernel<<<dim3(256, 8), bt, 0, stream>>>(C, wq + (size_t)i * 4096, temp_q, kv, se, Dt, i);
        // C = GELU(Dt @ out_w1 + out_b1)
        gemm_mfma<false, false, true, false, false, false><<<gg, bt, 0, stream>>>(
            Dt, wtL + (size_t)(5 + i) * 65536, out_b1 + i * 256, nullptr, C, nullptr, nullptr,
            nullptr, nullptr, nullptr, nullptr, nullptr, 256);
        // fx += C @ out_w2 + out_b2   (+stats for ln2)
        gemm_mfma<false, false, false, true, true, false><<<gg, bt, 0, stream>>>(
            C, wtL + (size_t)(10 + i) * 65536, out_b2 + i * 256, nullptr, fx, nullptr, st,
            nullptr, nullptr, nullptr, nullptr, nullptr, 256);
        // Dt = GELU( LN(fx;ln2) @ mlp_w1 + mlp_b1 )
        gemm_mfma<false, true, true, false, false, false><<<gg, bt, 0, stream>>>(
            fx, wtL + (size_t)(15 + i) * 65536, mlp_b1 + i * 256, nullptr, Dt, st, nullptr,
            ln2_g + i * 256, ln2_b + i * 256, nullptr, nullptr, nullptr, 256);
        // fx += Dt @ mlp_w2 + mlp_b2  (+stats for next ln1)
        gemm_mfma<false, false, false, true, true, false><<<gg, bt, 0, stream>>>(
            Dt, wtL + (size_t)(20 + i) * 65536, mlp_b2 + i * 256, nullptr, fx, nullptr, st,
            nullptr, nullptr, nullptr, nullptr, nullptr, 256);
    }
    head_kernel<<<dim3(NP / 4), bt, 0, stream>>>(fx, ln3_g, ln3_b, head_w, head_b, out);
}

// Round 9
// 1612.185 us; speedup vs baseline: 2.6194x; 1.0483x over previous
//
#include <hip/hip_runtime.h>
#include <hip/hip_bf16.h>
#include <math.h>

constexpr int NP  = 32768;  // mesh points
constexpr int HH  = 8;      // heads

typedef short bf16x8 __attribute__((ext_vector_type(8)));
typedef float f32x4  __attribute__((ext_vector_type(4)));

__device__ __forceinline__ float gelu_f(float x) {
    return 0.5f * x * (1.0f + erff(x * 0.70710678118654752f));
}

__device__ __forceinline__ unsigned short f2bf(float x) {
    union { float f; unsigned u; } v; v.f = x;
    unsigned r = v.u + 0x7fffu + ((v.u >> 16) & 1u);
    return (unsigned short)(r >> 16);
}

// ---------------------------------------------------------------------------
// Weight prep: src [G][K][256] fp32 -> dst [G][256][K] bf16 (transposed)
// ---------------------------------------------------------------------------
__global__ __launch_bounds__(256) void transpose_bf16_k(
    const float* __restrict__ src, unsigned short* __restrict__ dst, int K)
{
    __shared__ float tile[32][33];
    int g = blockIdx.z;
    int k0 = blockIdx.x * 32, c0 = blockIdx.y * 32;
    int tx = threadIdx.x & 31, ty = threadIdx.x >> 5;
    const float* s = src + (size_t)g * K * 256;
    unsigned short* d = dst + (size_t)g * 256 * K;
    #pragma unroll
    for (int rr = 0; rr < 4; ++rr) {
        int r = ty + rr * 8;
        tile[r][tx] = s[(size_t)(k0 + r) * 256 + c0 + tx];
    }
    __syncthreads();
    #pragma unroll
    for (int rr = 0; rr < 4; ++rr) {
        int r = ty + rr * 8;
        d[(size_t)(c0 + r) * K + k0 + tx] = f2bf(tile[tx][r]);
    }
}

// ---------------------------------------------------------------------------
// MFMA GEMM (unchanged): C = epi( A'[N x K] @ W[K x 256] + bias )
// ---------------------------------------------------------------------------
template<bool GENA, bool LNIN, bool DOGELU, bool RESID, bool STATS, bool PERM>
__global__ __launch_bounds__(256) void gemm_mfma(
    const float* __restrict__ A, const unsigned short* __restrict__ Wt,
    const float* __restrict__ bias, const float* __restrict__ bias2,
    float* __restrict__ Cout,
    const float* __restrict__ stats_in, float* __restrict__ stats_out,
    const float* __restrict__ lng, const float* __restrict__ lnb,
    const float* __restrict__ genx, const float* __restrict__ genw1,
    const float* __restrict__ genb1, int K)
{
    __shared__ __align__(16) unsigned short As[128 * 64];
    __shared__ __align__(16) unsigned short Bs[128 * 64];
    __shared__ float rmean[LNIN ? 128 : 1];
    __shared__ float rrstd[LNIN ? 128 : 1];
    __shared__ float w1s[GENA ? 1536 : 1];
    __shared__ float b1s[GENA ? 512 : 1];
    __shared__ float x3s[GENA ? 512 : 1];

    const int tid = threadIdx.x;
    const int rBase = blockIdx.x * 128, cBase = blockIdx.y * 128;

    if constexpr (GENA) {
        for (int i2 = tid; i2 < 1536; i2 += 256) w1s[i2] = genw1[i2];
        for (int i2 = tid; i2 < 512; i2 += 256) b1s[i2] = genb1[i2];
        if (tid < 128) {
            x3s[tid * 4 + 0] = genx[(size_t)(rBase + tid) * 3 + 0];
            x3s[tid * 4 + 1] = genx[(size_t)(rBase + tid) * 3 + 1];
            x3s[tid * 4 + 2] = genx[(size_t)(rBase + tid) * 3 + 2];
        }
        __syncthreads();
    }
    if constexpr (LNIN) {
        if (tid < 128) {
            const float* sp = stats_in + (size_t)(rBase + tid) * 8;
            float4 s0 = *(const float4*)sp;
            float4 s1 = *(const float4*)(sp + 4);
            float mean = (s0.x + s0.z + s1.x + s1.z) * (1.f / 256.f);
            float ex2  = (s0.y + s0.w + s1.y + s1.w) * (1.f / 256.f);
            rmean[tid] = mean;
            rrstd[tid] = rsqrtf(fmaxf(ex2 - mean * mean, 0.f) + 1e-5f);
        }
        __syncthreads();
    }

    f32x4 acc[4][4];
    #pragma unroll
    for (int i = 0; i < 4; ++i)
        #pragma unroll
        for (int j = 0; j < 4; ++j)
            acc[i][j] = (f32x4){0.f, 0.f, 0.f, 0.f};

    const int lane = tid & 63, wid = tid >> 6;
    const int wr = wid >> 1, wc = wid & 1;
    const int lrow = lane & 15, quad = lane >> 4;
    const int srow = tid >> 3;   // 0..31
    const int sch  = tid & 7;    // k-chunk of 8

    for (int kc = 0; kc < K; kc += 64) {
        #pragma unroll
        for (int it = 0; it < 4; ++it) {
            int row = srow + it * 32;
            float v[8];
            if constexpr (GENA) {
                float x0 = x3s[row * 4 + 0], x1 = x3s[row * 4 + 1], x2 = x3s[row * 4 + 2];
                #pragma unroll
                for (int j = 0; j < 8; ++j) {
                    int k = kc + sch * 8 + j;
                    float t = x0 * w1s[k] + x1 * w1s[512 + k] + x2 * w1s[1024 + k] + b1s[k];
                    v[j] = gelu_f(t);
                }
            } else {
                const float* ap = A + (size_t)(rBase + row) * 256 + kc + sch * 8;
                float4 a0 = *(const float4*)ap;
                float4 a1 = *(const float4*)(ap + 4);
                v[0] = a0.x; v[1] = a0.y; v[2] = a0.z; v[3] = a0.w;
                v[4] = a1.x; v[5] = a1.y; v[6] = a1.z; v[7] = a1.w;
                if constexpr (LNIN) {
                    float m = rmean[row], rs = rrstd[row];
                    const float* gp = lng + kc + sch * 8;
                    const float* bp = lnb + kc + sch * 8;
                    float4 g0 = *(const float4*)gp, g1 = *(const float4*)(gp + 4);
                    float4 c0 = *(const float4*)bp, c1 = *(const float4*)(bp + 4);
                    float gg[8] = {g0.x, g0.y, g0.z, g0.w, g1.x, g1.y, g1.z, g1.w};
                    float bb[8] = {c0.x, c0.y, c0.z, c0.w, c1.x, c1.y, c1.z, c1.w};
                    #pragma unroll
                    for (int j = 0; j < 8; ++j) v[j] = (v[j] - m) * rs * gg[j] + bb[j];
                }
            }
            unsigned short pk[8];
            #pragma unroll
            for (int j = 0; j < 8; ++j) pk[j] = f2bf(v[j]);
            *(uint4*)&As[row * 64 + ((sch ^ (row & 7)) << 3)] = *(uint4*)pk;
        }
        #pragma unroll
        for (int it = 0; it < 4; ++it) {
            int n = srow + it * 32;
            uint4 wv_ = *(const uint4*)(Wt + (size_t)(cBase + n) * K + kc + sch * 8);
            *(uint4*)&Bs[n * 64 + ((sch ^ (n & 7)) << 3)] = wv_;
        }
        __syncthreads();
        #pragma unroll
        for (int ks = 0; ks < 2; ++ks) {
            bf16x8 af[4], bfr[4];
            #pragma unroll
            for (int t = 0; t < 4; ++t) {
                int row = wr * 64 + t * 16 + lrow;
                af[t] = *(bf16x8*)&As[row * 64 + (((ks * 4 + quad) ^ (row & 7)) << 3)];
                int n = wc * 64 + t * 16 + lrow;
                bfr[t] = *(bf16x8*)&Bs[n * 64 + (((ks * 4 + quad) ^ (n & 7)) << 3)];
            }
            #pragma unroll
            for (int ti = 0; ti < 4; ++ti)
                #pragma unroll
                for (int tj = 0; tj < 4; ++tj)
                    acc[ti][tj] = __builtin_amdgcn_mfma_f32_16x16x32_bf16(
                        af[ti], bfr[tj], acc[ti][tj], 0, 0, 0);
        }
        __syncthreads();
    }

    float bcol[4];
    #pragma unroll
    for (int tj = 0; tj < 4; ++tj) {
        int gcol = cBase + wc * 64 + tj * 16 + lrow;
        float b = bias[gcol];
        if (bias2) b += bias2[gcol];
        bcol[tj] = b;
    }
    #pragma unroll
    for (int ti = 0; ti < 4; ++ti) {
        #pragma unroll
        for (int r = 0; r < 4; ++r) {
            int grow = rBase + wr * 64 + ti * 16 + quad * 4 + r;
            float vv[4];
            #pragma unroll
            for (int tj = 0; tj < 4; ++tj) {
                float v = acc[ti][tj][r] + bcol[tj];
                if constexpr (DOGELU) v = gelu_f(v);
                vv[tj] = v;
            }
            if constexpr (RESID) {
                #pragma unroll
                for (int tj = 0; tj < 4; ++tj) {
                    int gcol = cBase + wc * 64 + tj * 16 + lrow;
                    vv[tj] += Cout[(size_t)grow * 256 + gcol];
                }
            }
            if constexpr (STATS) {
                float rs = vv[0] + vv[1] + vv[2] + vv[3];
                float rq = vv[0]*vv[0] + vv[1]*vv[1] + vv[2]*vv[2] + vv[3]*vv[3];
                #pragma unroll
                for (int m = 1; m < 16; m <<= 1) {
                    rs += __shfl_xor(rs, m);
                    rq += __shfl_xor(rq, m);
                }
                if (lrow == 0) {
                    stats_out[(size_t)grow * 8 + (blockIdx.y * 2 + wc) * 2 + 0] = rs;
                    stats_out[(size_t)grow * 8 + (blockIdx.y * 2 + wc) * 2 + 1] = rq;
                }
            }
            #pragma unroll
            for (int tj = 0; tj < 4; ++tj) {
                int gcol = cBase + wc * 64 + tj * 16 + lrow;
                if constexpr (PERM)
                    Cout[(size_t)(gcol >> 5) * NP * 32 + (size_t)grow * 32 + (gcol & 31)] = vv[tj];
                else
                    Cout[(size_t)grow * 256 + gcol] = vv[tj];
            }
        }
    }
}

// ---------------------------------------------------------------------------
// kv5 (R9): kv3 + wk hoisted into registers. R8 counters showed the logit
// loop's 32x ds_read_b64 of the loop-invariant wk pair = 16 KB LDS traffic
// per row per wave (~55 us of LDS pipe occupancy per dispatch). wkr0/wkr1
// are loaded once from global (coalesced float2, L2-cached); logits become
// pure register FMAs. LDS drops 36->20 KB. Plain __launch_bounds__(512)
// (no min-wave hint -> no forced 64-VGPR cap, the R6 lesson); needs ~160
// VGPR, fits the 8-wave 256-VGPR ceiling. Summation order identical to kv3.
// partials layout: [h][chunk][4224] = 128*32 kv + 128 sumexp
// ---------------------------------------------------------------------------
__global__ __launch_bounds__(512) void kv5_kernel(
    const float* __restrict__ xm2, const float* __restrict__ wk,
    const float* __restrict__ wv, const float* __restrict__ tk_arr,
    float* __restrict__ partials, int layer)
{
    __shared__ __align__(16) float smem[5120];
    float* xs  = smem;            // [64][32]
    float* vs  = smem + 2048;     // [64][32]
    float* wvs = smem + 4096;     // [32][32]
    float* red = smem;            // [512][9] alias (4608 <= 5120, after loop)

    const int tid = threadIdx.x;
    const int h = blockIdx.y;
    const int rowBase = blockIdx.x * 512;
    const int p  = tid >> 6;
    const int dg = tid & 63;

    float tk = fminf(fmaxf(tk_arr[layer * 8 + h], 0.1f), 2.0f);
    float invtk = 1.0f / tk;
    for (int i = tid; i < 1024; i += 512) wvs[i] = wv[i];

    // wk columns (d = 2dg, 2dg+1) into registers: 64 floats, loop-invariant
    float wkr0[32], wkr1[32];
    #pragma unroll
    for (int j = 0; j < 32; ++j) {
        float2 w2 = *(const float2*)(wk + j * 128 + dg * 2);
        wkr0[j] = w2.x; wkr1[j] = w2.y;
    }

    float acc0[32], acc1[32];
    #pragma unroll
    for (int c = 0; c < 32; ++c) { acc0[c] = 0.f; acc1[c] = 0.f; }
    float se0 = 0.f, se1 = 0.f;

    const float* src = xm2 + (size_t)h * NP * 32 + (size_t)rowBase * 32;
    const int lr = tid >> 3, lc = (tid & 7) * 4;

    for (int tile = 0; tile < 8; ++tile) {
        __syncthreads();
        *(float4*)&xs[lr * 32 + lc] =
            *(const float4*)(src + (size_t)(tile * 64 + lr) * 32 + lc);
        __syncthreads();
        {
            float a0 = 0.f, a1 = 0.f, a2 = 0.f, a3 = 0.f;
            #pragma unroll
            for (int j = 0; j < 32; ++j) {
                float xv = xs[lr * 32 + j];
                float4 w4 = *(const float4*)&wvs[j * 32 + lc];
                a0 += xv * w4.x; a1 += xv * w4.y; a2 += xv * w4.z; a3 += xv * w4.w;
            }
            float4 o; o.x = a0; o.y = a1; o.z = a2; o.w = a3;
            *(float4*)&vs[lr * 32 + lc] = o;
        }
        __syncthreads();
        #pragma unroll 1
        for (int t = 0; t < 8; ++t) {
            int n = p * 8 + t;
            float l0 = 0.f, l1 = 0.f;
            #pragma unroll
            for (int j4 = 0; j4 < 8; ++j4) {
                float4 x4 = *(const float4*)&xs[n * 32 + j4 * 4];   // broadcast
                l0 += x4.x * wkr0[j4 * 4 + 0] + x4.y * wkr0[j4 * 4 + 1]
                    + x4.z * wkr0[j4 * 4 + 2] + x4.w * wkr0[j4 * 4 + 3];
                l1 += x4.x * wkr1[j4 * 4 + 0] + x4.y * wkr1[j4 * 4 + 1]
                    + x4.z * wkr1[j4 * 4 + 2] + x4.w * wkr1[j4 * 4 + 3];
            }
            float e0 = __expf(fminf(fmaxf(l0 * invtk, -60.f), 60.f));
            float e1 = __expf(fminf(fmaxf(l1 * invtk, -60.f), 60.f));
            se0 += e0; se1 += e1;
            #pragma unroll
            for (int cc = 0; cc < 8; ++cc) {
                float4 v4 = *(const float4*)&vs[n * 32 + cc * 4];   // broadcast
                acc0[cc*4+0] += e0 * v4.x; acc0[cc*4+1] += e0 * v4.y;
                acc0[cc*4+2] += e0 * v4.z; acc0[cc*4+3] += e0 * v4.w;
                acc1[cc*4+0] += e1 * v4.x; acc1[cc*4+1] += e1 * v4.y;
                acc1[cc*4+2] += e1 * v4.z; acc1[cc*4+3] += e1 * v4.w;
            }
        }
    }

    // deterministic cross-wave reduction (fully unrolled, compile-time idx)
    float* outp = partials + ((size_t)h * 64 + blockIdx.x) * 4224;
    #pragma unroll
    for (int cc = 0; cc < 8; ++cc) {
        __syncthreads();
        #pragma unroll
        for (int ci = 0; ci < 4; ++ci) {
            red[tid * 9 + ci]     = acc0[cc * 4 + ci];
            red[tid * 9 + 4 + ci] = acc1[cc * 4 + ci];
        }
        __syncthreads();
        int d = tid >> 2, ci = tid & 3;
        float s = 0.f;
        #pragma unroll
        for (int pp = 0; pp < 8; ++pp)
            s += red[(pp * 64 + (d >> 1)) * 9 + (d & 1) * 4 + ci];
        outp[d * 32 + cc * 4 + ci] = s;
    }
    __syncthreads();
    red[tid * 9 + 0] = se0;
    red[tid * 9 + 1] = se1;
    __syncthreads();
    if (tid < 128) {
        int d = tid;
        float s = 0.f;
        #pragma unroll
        for (int pp = 0; pp < 8; ++pp)
            s += red[(pp * 64 + (d >> 1)) * 9 + (d & 1)];
        outp[4096 + d] = s;
    }
}

__global__ __launch_bounds__(256) void kv_reduce_kernel(
    const float* __restrict__ partials, float* __restrict__ kvU,
    float* __restrict__ sumexp)
{
    int gid = blockIdx.x * 256 + threadIdx.x;
    if (gid >= 8 * 4224) return;
    int h = gid / 4224, idx = gid % 4224;
    const float* base = partials + (size_t)h * 64 * 4224 + idx;
    float s = 0.f;
    #pragma unroll 8
    for (int c = 0; c < 64; ++c) s += base[(size_t)c * 4224];
    if (idx < 4096) kvU[(size_t)h * 4096 + idx] = s;
    else sumexp[h * 128 + (idx - 4096)] = s;
}

// ---------------------------------------------------------------------------
// qkv3 (unchanged, working): balanced 8x8 register tiling, swizzled LDS,
// shfl softmax, reduce-scatter PV.
// ---------------------------------------------------------------------------
__global__ __launch_bounds__(256) void qkv3_kernel(
    const float* __restrict__ xm2, const float* __restrict__ wq,
    const float* __restrict__ tq_arr,
    const float* __restrict__ kvU, const float* __restrict__ sumexp,
    float* __restrict__ outD, int layer)
{
    __shared__ __align__(16) float xsw[4096];
    __shared__ __align__(16) float wqs[4096];
    __shared__ __align__(16) float kvs[4096];
    __shared__ float ises[128];

    const int tid = threadIdx.x;
    const int h = blockIdx.y;
    const int rowBase = blockIdx.x * 128;
    const int rt = tid >> 4;
    const int dt = tid & 15;

    float tq = fminf(fmaxf(tq_arr[layer * 8 + h], 0.1f), 2.0f);
    float invtq = 1.0f / tq;

    if (tid < 128) ises[tid] = 1.0f / sumexp[h * 128 + tid];
    #pragma unroll
    for (int it = 0; it < 4; ++it) {
        int i4 = tid + it * 256;
        int k = i4 >> 5, c4 = i4 & 31;
        float4 v = *(const float4*)(wq + (size_t)k * 128 + c4 * 4);
        int c4s = c4 ^ ((c4 >> 1) & 7);
        *(float4*)&wqs[k * 128 + c4s * 4] = v;
    }
    {
        const float* kvsrc = kvU + (size_t)h * 4096;
        #pragma unroll
        for (int it = 0; it < 4; ++it) {
            int i4 = tid + it * 256;
            int d = i4 >> 3, c4 = i4 & 7;
            float4 v = *(const float4*)(kvsrc + (size_t)d * 32 + c4 * 4);
            int c4s = c4 ^ ((d >> 3) & 7);
            *(float4*)&kvs[d * 32 + c4s * 4] = v;
        }
    }
    {
        const float* src = xm2 + (size_t)h * NP * 32 + (size_t)rowBase * 32;
        #pragma unroll
        for (int it = 0; it < 4; ++it) {
            int s = tid + it * 256;
            int r = s >> 3, j4 = s & 7;
            float4 v = *(const float4*)(src + (size_t)r * 32 + j4 * 4);
            *(float4*)&xsw[r * 32 + ((j4 ^ ((r >> 3) & 7)) << 2)] = v;
        }
    }
    __syncthreads();

    const int swr = rt & 7;
    const int swd = dt & 7;

    float l[8][8];
    #pragma unroll
    for (int i = 0; i < 8; ++i)
        #pragma unroll
        for (int jd = 0; jd < 8; ++jd) l[i][jd] = 0.f;

    const int cA = (dt * 2)     ^ swd;
    const int cB = (dt * 2 + 1) ^ swd;
    #pragma unroll
    for (int j4 = 0; j4 < 8; ++j4) {
        float4 xv[8];
        #pragma unroll
        for (int i = 0; i < 8; ++i)
            xv[i] = *(const float4*)&xsw[(rt * 8 + i) * 32 + ((j4 ^ swr) << 2)];
        #pragma unroll
        for (int kk = 0; kk < 4; ++kk) {
            int k = j4 * 4 + kk;
            float4 wa = *(const float4*)&wqs[k * 128 + cA * 4];
            float4 wb = *(const float4*)&wqs[k * 128 + cB * 4];
            #pragma unroll
            for (int i = 0; i < 8; ++i) {
                float xx = (kk == 0) ? xv[i].x : (kk == 1) ? xv[i].y
                         : (kk == 2) ? xv[i].z : xv[i].w;
                l[i][0] += xx * wa.x; l[i][1] += xx * wa.y;
                l[i][2] += xx * wa.z; l[i][3] += xx * wa.w;
                l[i][4] += xx * wb.x; l[i][5] += xx * wb.y;
                l[i][6] += xx * wb.z; l[i][7] += xx * wb.w;
            }
        }
    }

    float isr[8];
    #pragma unroll
    for (int jd = 0; jd < 8; ++jd) isr[jd] = ises[dt * 8 + jd];
    #pragma unroll
    for (int i = 0; i < 8; ++i) {
        float m = l[i][0];
        #pragma unroll
        for (int jd = 1; jd < 8; ++jd) m = fmaxf(m, l[i][jd]);
        m = fmaxf(m, __shfl_xor(m, 1));
        m = fmaxf(m, __shfl_xor(m, 2));
        m = fmaxf(m, __shfl_xor(m, 4));
        m = fmaxf(m, __shfl_xor(m, 8));
        float s = 0.f;
        #pragma unroll
        for (int jd = 0; jd < 8; ++jd) {
            float e = __expf((l[i][jd] - m) * invtq);
            l[i][jd] = e;
            s += e;
        }
        s += __shfl_xor(s, 1);
        s += __shfl_xor(s, 2);
        s += __shfl_xor(s, 4);
        s += __shfl_xor(s, 8);
        float inv = 1.0f / s;
        #pragma unroll
        for (int jd = 0; jd < 8; ++jd) l[i][jd] *= inv * isr[jd];
    }

    const int b0 = dt & 1, b1 = (dt >> 1) & 1, b2 = (dt >> 2) & 1, b3 = (dt >> 3) & 1;
    #pragma unroll
    for (int chunk = 0; chunk < 4; ++chunk) {
        float o[8][8];
        #pragma unroll
        for (int i = 0; i < 8; ++i)
            #pragma unroll
            for (int c = 0; c < 8; ++c) o[i][c] = 0.f;
        const int kA = (chunk * 2)     ^ swd;
        const int kB = (chunk * 2 + 1) ^ swd;
        #pragma unroll
        for (int jd = 0; jd < 8; ++jd) {
            int d = dt * 8 + jd;
            float4 ka = *(const float4*)&kvs[d * 32 + kA * 4];
            float4 kb = *(const float4*)&kvs[d * 32 + kB * 4];
            #pragma unroll
            for (int i = 0; i < 8; ++i) {
                float p = l[i][jd];
                o[i][0] += p * ka.x; o[i][1] += p * ka.y;
                o[i][2] += p * ka.z; o[i][3] += p * ka.w;
                o[i][4] += p * kb.x; o[i][5] += p * kb.y;
                o[i][6] += p * kb.z; o[i][7] += p * kb.w;
            }
        }
        float t1[4][8];
        #pragma unroll
        for (int i = 0; i < 4; ++i)
            #pragma unroll
            for (int c = 0; c < 8; ++c) {
                float keep = b0 ? o[i + 4][c] : o[i][c];
                float send = b0 ? o[i][c] : o[i + 4][c];
                t1[i][c] = keep + __shfl_xor(send, 1);
            }
        float t2[2][8];
        #pragma unroll
        for (int i = 0; i < 2; ++i)
            #pragma unroll
            for (int c = 0; c < 8; ++c) {
                float keep = b1 ? t1[i + 2][c] : t1[i][c];
                float send = b1 ? t1[i][c] : t1[i + 2][c];
                t2[i][c] = keep + __shfl_xor(send, 2);
            }
        float t3[2][4];
        #pragma unroll
        for (int i = 0; i < 2; ++i)
            #pragma unroll
            for (int c = 0; c < 4; ++c) {
                float keep = b2 ? t2[i][c + 4] : t2[i][c];
                float send = b2 ? t2[i][c] : t2[i][c + 4];
                t3[i][c] = keep + __shfl_xor(send, 4);
            }
        float t4[4];
        #pragma unroll
        for (int c = 0; c < 4; ++c) {
            float keep = b3 ? t3[1][c] : t3[0][c];
            float send = b3 ? t3[0][c] : t3[1][c];
            t4[c] = keep + __shfl_xor(send, 8);
        }
        int row = rt * 8 + b0 * 4 + b1 * 2 + b3;
        float4 ov; ov.x = t4[0]; ov.y = t4[1]; ov.z = t4[2]; ov.w = t4[3];
        *(float4*)(outD + (size_t)(rowBase + row) * 256 + h * 32 + chunk * 8 + b2 * 4) = ov;
    }
}

// ---------------------------------------------------------------------------
// head: out[n] = LN(fx[n]; ln3) . head_w + head_b
// ---------------------------------------------------------------------------
__global__ __launch_bounds__(256) void head_kernel(
    const float* __restrict__ fx, const float* __restrict__ g, const float* __restrict__ b,
    const float* __restrict__ hw, const float* __restrict__ hb, float* __restrict__ out)
{
    int lane = threadIdx.x & 63;
    int row = blockIdx.x * 4 + (threadIdx.x >> 6);
    float4 v = *(const float4*)(fx + (size_t)row * 256 + lane * 4);
    float s1 = v.x + v.y + v.z + v.w;
    float s2 = v.x * v.x + v.y * v.y + v.z * v.z + v.w * v.w;
    #pragma unroll
    for (int m = 1; m < 64; m <<= 1) { s1 += __shfl_xor(s1, m); s2 += __shfl_xor(s2, m); }
    float mean = s1 * 0.00390625f;
    float rstd = rsqrtf(fmaxf(s2 * 0.00390625f - mean * mean, 0.f) + 1e-5f);
    float4 gg = *(const float4*)(g + lane * 4);
    float4 bb = *(const float4*)(b + lane * 4);
    float4 w4 = *(const float4*)(hw + lane * 4);
    float d = ((v.x - mean) * rstd * gg.x + bb.x) * w4.x
            + ((v.y - mean) * rstd * gg.y + bb.y) * w4.y
            + ((v.z - mean) * rstd * gg.z + bb.z) * w4.z
            + ((v.w - mean) * rstd * gg.w + bb.w) * w4.w;
    #pragma unroll
    for (int m = 1; m < 64; m <<= 1) d += __shfl_xor(d, m);
    if (lane == 0) out[row] = d + hb[0];
}

extern "C" void kernel_launch(void* const* d_in, const int* in_sizes, int n_in,
                              void* d_out, int out_size, void* d_ws, size_t ws_size,
                              hipStream_t stream)
{
    const float* x      = (const float*)d_in[0];
    const float* pre_w1 = (const float*)d_in[1];
    const float* pre_b1 = (const float*)d_in[2];
    const float* pre_w2 = (const float*)d_in[3];
    const float* pre_b2 = (const float*)d_in[4];
    const float* ph     = (const float*)d_in[5];
    const float* ln1_g  = (const float*)d_in[6];
    const float* ln1_b  = (const float*)d_in[7];
    const float* inp_w  = (const float*)d_in[8];
    const float* inp_b  = (const float*)d_in[9];
    const float* temp_q = (const float*)d_in[10];
    const float* temp_k = (const float*)d_in[11];
    const float* wq     = (const float*)d_in[12];
    const float* wk     = (const float*)d_in[13];
    const float* wv     = (const float*)d_in[14];
    const float* out_w1 = (const float*)d_in[15];
    const float* out_b1 = (const float*)d_in[16];
    const float* out_w2 = (const float*)d_in[17];
    const float* out_b2 = (const float*)d_in[18];
    const float* ln2_g  = (const float*)d_in[19];
    const float* ln2_b  = (const float*)d_in[20];
    const float* mlp_w1 = (const float*)d_in[21];
    const float* mlp_b1 = (const float*)d_in[22];
    const float* mlp_w2 = (const float*)d_in[23];
    const float* mlp_b2 = (const float*)d_in[24];
    const float* ln3_g  = (const float*)d_in[25];
    const float* ln3_b  = (const float*)d_in[26];
    const float* head_w = (const float*)d_in[27];
    const float* head_b = (const float*)d_in[28];
    float* out = (float*)d_out;

    // ws layout (floats): fx | C | Dt | stats | kvU | se | WtPre | WtL
    float* fx = (float*)d_ws;
    float* C  = fx + (size_t)NP * 256;
    float* Dt = C  + (size_t)NP * 256;
    float* st = Dt + (size_t)NP * 256;
    float* kv = st + (size_t)NP * 8;
    float* se = kv + 8 * 4096;
    unsigned short* wtPre = (unsigned short*)(se + 8 * 128);
    unsigned short* wtL   = wtPre + 256 * 512;     // 25 x [256][256]
    float* partials = Dt;                          // alias (Dt dead during kv)

    dim3 bt(256);

    // weight prep (bf16, transposed)
    transpose_bf16_k<<<dim3(16, 8, 1), bt, 0, stream>>>(pre_w2, wtPre, 512);
    transpose_bf16_k<<<dim3(8, 8, 5), bt, 0, stream>>>(inp_w,  wtL +  0 * 65536, 256);
    transpose_bf16_k<<<dim3(8, 8, 5), bt, 0, stream>>>(out_w1, wtL +  5 * 65536, 256);
    transpose_bf16_k<<<dim3(8, 8, 5), bt, 0, stream>>>(out_w2, wtL + 10 * 65536, 256);
    transpose_bf16_k<<<dim3(8, 8, 5), bt, 0, stream>>>(mlp_w1, wtL + 15 * 65536, 256);
    transpose_bf16_k<<<dim3(8, 8, 5), bt, 0, stream>>>(mlp_w2, wtL + 20 * 65536, 256);

    dim3 gg(256, 2);

    // preprocess: fx = GELU(x@pre_w1+pre_b1)@pre_w2 + pre_b2 + placeholder (+stats)
    gemm_mfma<true, false, false, false, true, false><<<gg, bt, 0, stream>>>(
        nullptr, wtPre, pre_b2, ph, fx, nullptr, st, nullptr, nullptr,
        x, pre_w1, pre_b1, 512);

    for (int i = 0; i < 5; ++i) {
        // xm2 = perm( LN(fx;ln1) @ inp_w + inp_b )
        gemm_mfma<false, true, false, false, false, true><<<gg, bt, 0, stream>>>(
            fx, wtL + (size_t)(0 + i) * 65536, inp_b + i * 256, nullptr, C, st, nullptr,
            ln1_g + i * 256, ln1_b + i * 256, nullptr, nullptr, nullptr, 256);
        // kv partials + reduce
        kv5_kernel<<<dim3(64, 8), dim3(512), 0, stream>>>(
            C, wk + (size_t)i * 4096, wv + (size_t)i * 1024, temp_k, partials, i);
        kv_reduce_kernel<<<dim3(132), bt, 0, stream>>>(partials, kv, se);
        // qkv -> Dt [N,256]
        qkv3_kernel<<<dim3(256, 8), bt, 0, stream>>>(C, wq + (size_t)i * 4096, temp_q, kv, se, Dt, i);
        // C = GELU(Dt @ out_w1 + out_b1)
        gemm_mfma<false, false, true, false, false, false><<<gg, bt, 0, stream>>>(
            Dt, wtL + (size_t)(5 + i) * 65536, out_b1 + i * 256, nullptr, C, nullptr, nullptr,
            nullptr, nullptr, nullptr, nullptr, nullptr, 256);
        // fx += C @ out_w2 + out_b2   (+stats for ln2)
        gemm_mfma<false, false, false, true, true, false><<<gg, bt, 0, stream>>>(
            C, wtL + (size_t)(10 + i) * 65536, out_b2 + i * 256, nullptr, fx, nullptr, st,
            nullptr, nullptr, nullptr, nullptr, nullptr, 256);
        // Dt = GELU( LN(fx;ln2) @ mlp_w1 + mlp_b1 )
        gemm_mfma<false, true, true, false, false, false><<<gg, bt, 0, stream>>>(
            fx, wtL + (size_t)(15 + i) * 65536, mlp_b1 + i * 256, nullptr, Dt, st, nullptr,
            ln2_g + i * 256, ln2_b + i * 256, nullptr, nullptr, nullptr, 256);
        // fx += Dt @ mlp_w2 + mlp_b2  (+stats for next ln1)
        gemm_mfma<false, false, false, true, true, false><<<gg, bt, 0, stream>>>(
            Dt, wtL + (size_t)(20 + i) * 65536, mlp_b2 + i * 256, nullptr, fx, nullptr, st,
            nullptr, nullptr, nullptr, nullptr, nullptr, 256);
    }
    head_kernel<<<dim3(NP / 4), bt, 0, stream>>>(fx, ln3_g, ln3_b, head_w, head_b, out);
}